// Round 1
// baseline (1636.719 us; speedup 1.0000x reference)
//
#include <hip/hip_runtime.h>

#define NG 64
#define DC 128
#define DP 32
#define DH 512
#define MTOT 2048
#define TT 64
#define NTILE 32

// output offsets (floats), in reference return order
static constexpr size_t OFF_XOUT = 0;
static constexpr size_t OFF_Z    = 16777216;
static constexpr size_t OFF_ZHAT = 20971520;
static constexpr size_t OFF_SUR  = 25165824;
static constexpr size_t OFF_KC   = 25296896;
static constexpr size_t OFF_VP   = 42074112;
static constexpr size_t OFF_GATE = 58851328;
static constexpr size_t OFF_QN   = 58982400;
static constexpr size_t OFF_VC   = 75759616;
static constexpr size_t OFF_WN   = 92536832;
static constexpr size_t OFF_S5   = 92667904;

// ---------------- Kernel 1: encode + surprise + gain + LN -> h ----------------
__global__ __launch_bounds__(256)
void k1_encode_ln(const float* __restrict__ x_col,
                  const float* __restrict__ z_hat_prev,
                  const float* __restrict__ gamma,
                  const float* __restrict__ beta,
                  const float* __restrict__ W_enc, const float* __restrict__ b_enc,
                  const float* __restrict__ W_pred, const float* __restrict__ b_pred,
                  const float* __restrict__ W_gain, const float* __restrict__ b_gain,
                  float* out)
{
    const int tile = blockIdx.x, g = blockIdx.y, tid = threadIdx.x;
    const int m0 = tile * TT;

    __shared__ float sWenc[DC * DP];   // [k][o]
    __shared__ float sWpred[DP * DP];  // [k][o]
    __shared__ float sWgain[DP * DC];  // [o][j]
    __shared__ float sbenc[DP], sbpred[DP];
    __shared__ float sbgain[DC], sgamma[DC], sbeta[DC];
    __shared__ float sX[TT * 132];     // padded
    __shared__ float sZ[TT * DP];
    __shared__ float sD[TT * DP];      // z_hat_prev then delta
    __shared__ float sMu[TT], sRstd[TT];

    for (int i = tid; i < DC * DP; i += 256) sWenc[i] = W_enc[(size_t)g * DC * DP + i];
    for (int i = tid; i < DP * DP; i += 256) sWpred[i] = W_pred[(size_t)g * DP * DP + i];
    for (int i = tid; i < DP * DC; i += 256) sWgain[i] = W_gain[(size_t)g * DP * DC + i];
    if (tid < DP) { sbenc[tid] = b_enc[g * DP + tid]; sbpred[tid] = b_pred[g * DP + tid]; }
    for (int i = tid; i < DC; i += 256) {
        sbgain[i] = b_gain[g * DC + i];
        sgamma[i] = gamma[g * DC + i];
        sbeta[i]  = beta[g * DC + i];
    }
    for (int idx = tid; idx < TT * 32; idx += 256) {     // x tile
        int t = idx >> 5, q = idx & 31;
        float4 v = *(const float4*)&x_col[(size_t)(m0 + t) * 8192 + g * 128 + q * 4];
        *(float4*)&sX[t * 132 + q * 4] = v;
    }
    for (int idx = tid; idx < TT * 8; idx += 256) {      // z_hat_prev tile
        int t = idx >> 3, q = idx & 7;
        float4 v = *(const float4*)&z_hat_prev[(size_t)(m0 + t) * 2048 + g * 32 + q * 4];
        *(float4*)&sD[t * 32 + q * 4] = v;
    }
    __syncthreads();

    // z = x @ W_enc + b_enc
    for (int idx = tid; idx < TT * DP; idx += 256) {
        int t = idx >> 5, o = idx & 31;
        float acc = sbenc[o];
        const float* xr = &sX[t * 132];
        const float* wc = &sWenc[o];
        #pragma unroll 8
        for (int k = 0; k < DC; ++k) acc += xr[k] * wc[k * 32];
        sZ[t * 32 + o] = acc;
        out[OFF_Z + (size_t)(m0 + t) * 2048 + g * 32 + o] = acc;
    }
    __syncthreads();

    // delta, surprise (+gate, surprise5)
    for (int idx = tid; idx < TT * DP; idx += 256) {
        int t = idx >> 5, o = idx & 31;
        float d = sZ[t * 32 + o] - sD[t * 32 + o];
        sD[t * 32 + o] = d;
        float s = d * d;
        s += __shfl_xor(s, 1); s += __shfl_xor(s, 2); s += __shfl_xor(s, 4);
        s += __shfl_xor(s, 8); s += __shfl_xor(s, 16);
        if (o == 0) {
            float sur = sqrtf(s);
            size_t p = (size_t)(m0 + t) * 64 + g;
            out[OFF_SUR + p] = sur;
            out[OFF_S5 + p]  = sur;
            out[OFF_GATE + p] = fminf(fmaxf(sur, 0.f), 1.f);
        }
    }
    __syncthreads();

    // z_hat = z @ W_pred + b_pred
    for (int idx = tid; idx < TT * DP; idx += 256) {
        int t = idx >> 5, o = idx & 31;
        float acc = sbpred[o];
        #pragma unroll
        for (int k = 0; k < DP; ++k) acc += sZ[t * 32 + k] * sWpred[k * 32 + o];
        out[OFF_ZHAT + (size_t)(m0 + t) * 2048 + g * 32 + o] = acc;
    }

    // LN stats
    {
        int t = tid >> 2, part = tid & 3;
        float s1 = 0.f, s2 = 0.f;
        #pragma unroll 8
        for (int kk = 0; kk < 32; ++kk) {
            float v = sX[t * 132 + part * 32 + kk];
            s1 += v; s2 += v * v;
        }
        s1 += __shfl_xor(s1, 1); s1 += __shfl_xor(s1, 2);
        s2 += __shfl_xor(s2, 1); s2 += __shfl_xor(s2, 2);
        if (part == 0) {
            float mu = s1 * (1.f / 128.f);
            float var = s2 * (1.f / 128.f) - mu * mu;
            sMu[t] = mu;
            sRstd[t] = rsqrtf(var + 1e-5f);
        }
    }
    __syncthreads();

    // gain + LN apply -> h staged into x_out region
    for (int idx = tid; idx < TT * DC; idx += 256) {
        int t = idx >> 7, j = idx & 127;
        float ga = sbgain[j];
        #pragma unroll
        for (int o = 0; o < DP; ++o) ga += sD[t * 32 + o] * sWgain[o * 128 + j];
        float gain = 1.f + 0.1f * tanhf(ga);
        float xv = sX[t * 132 + j];
        float h = ((xv - sMu[t]) * sRstd[t] * sgamma[j] + sbeta[j]) * gain;
        out[OFF_XOUT + (size_t)(m0 + t) * 8192 + g * 128 + j] = h;
    }
}

// ---------------- Kernel 2: MLP (up+gelu+down) + residual ----------------
__global__ __launch_bounds__(256)
void k2_mlp(const float* __restrict__ x_col,
            const float* __restrict__ W_up, const float* __restrict__ b_up,
            const float* __restrict__ W_down, const float* __restrict__ b_down,
            float* out)
{
    const int tile = blockIdx.x, g = blockIdx.y, tid = threadIdx.x;
    const int m0 = tile * TT;

    __shared__ float sH[TT * 132];
    __shared__ float sWu[DC * 64];   // [k][c]
    __shared__ float sWd[64 * DC];   // [cc][j]
    __shared__ float sU[TT * 68];
    __shared__ float sbup[DH];

    for (int i = tid; i < DH; i += 256) sbup[i] = b_up[(size_t)g * DH + i];
    for (int idx = tid; idx < TT * 32; idx += 256) {     // h tile (from x_out region)
        int t = idx >> 5, q = idx & 31;
        float4 v = *(const float4*)&out[OFF_XOUT + (size_t)(m0 + t) * 8192 + g * 128 + q * 4];
        *(float4*)&sH[t * 132 + q * 4] = v;
    }

    const int cg = tid & 15, tb = tid >> 4;
    float accd[2][4][4];
    #pragma unroll
    for (int p = 0; p < 2; ++p)
        #pragma unroll
        for (int r = 0; r < 4; ++r)
            #pragma unroll
            for (int c = 0; c < 4; ++c) accd[p][r][c] = 0.f;

    for (int ch = 0; ch < 8; ++ch) {
        const int c0 = ch * 64;
        __syncthreads();
        for (int idx = tid; idx < DC * 16; idx += 256) {  // W_up chunk
            int k = idx >> 4, q = idx & 15;
            float4 v = *(const float4*)&W_up[(size_t)g * 65536 + (size_t)k * 512 + c0 + q * 4];
            *(float4*)&sWu[k * 64 + q * 4] = v;
        }
        for (int idx = tid; idx < 64 * 32; idx += 256) {  // W_down chunk
            int r = idx >> 5, q = idx & 31;
            float4 v = *(const float4*)&W_down[(size_t)g * 65536 + (size_t)(c0 + r) * 128 + q * 4];
            *(float4*)&sWd[r * 128 + q * 4] = v;
        }
        __syncthreads();

        // up GEMM 4t x 4c
        float acc[4][4];
        #pragma unroll
        for (int r = 0; r < 4; ++r)
            #pragma unroll
            for (int c = 0; c < 4; ++c) acc[r][c] = sbup[c0 + cg * 4 + c];
        for (int k0 = 0; k0 < DC; k0 += 4) {
            float4 hv[4];
            #pragma unroll
            for (int r = 0; r < 4; ++r) hv[r] = *(const float4*)&sH[(tb * 4 + r) * 132 + k0];
            #pragma unroll
            for (int kk = 0; kk < 4; ++kk) {
                float4 wv = *(const float4*)&sWu[(k0 + kk) * 64 + cg * 4];
                #pragma unroll
                for (int r = 0; r < 4; ++r) {
                    float h = ((const float*)&hv[r])[kk];
                    acc[r][0] += h * wv.x; acc[r][1] += h * wv.y;
                    acc[r][2] += h * wv.z; acc[r][3] += h * wv.w;
                }
            }
        }
        #pragma unroll
        for (int r = 0; r < 4; ++r)
            #pragma unroll
            for (int c = 0; c < 4; ++c) {
                float u = acc[r][c];
                float gel = 0.5f * u * (1.f + erff(u * 0.70710678f));
                sU[(tb * 4 + r) * 68 + cg * 4 + c] = gel;
            }
        __syncthreads();

        // down partial
        #pragma unroll
        for (int pass = 0; pass < 2; ++pass) {
            const int j4 = pass * 64 + cg * 4;
            for (int cc0 = 0; cc0 < 64; cc0 += 4) {
                float4 uv[4];
                #pragma unroll
                for (int r = 0; r < 4; ++r) uv[r] = *(const float4*)&sU[(tb * 4 + r) * 68 + cc0];
                #pragma unroll
                for (int kk = 0; kk < 4; ++kk) {
                    float4 wv = *(const float4*)&sWd[(cc0 + kk) * 128 + j4];
                    #pragma unroll
                    for (int r = 0; r < 4; ++r) {
                        float u = ((const float*)&uv[r])[kk];
                        accd[pass][r][0] += u * wv.x; accd[pass][r][1] += u * wv.y;
                        accd[pass][r][2] += u * wv.z; accd[pass][r][3] += u * wv.w;
                    }
                }
            }
        }
    }

    // x_out = x + b_down + h_mlp
    #pragma unroll
    for (int pass = 0; pass < 2; ++pass) {
        const int j4 = pass * 64 + cg * 4;
        #pragma unroll
        for (int r = 0; r < 4; ++r) {
            int t = tb * 4 + r;
            size_t base = (size_t)(m0 + t) * 8192 + g * 128 + j4;
            float4 xv = *(const float4*)&x_col[base];
            float4 bd = *(const float4*)&b_down[g * 128 + j4];
            float4 o4;
            o4.x = xv.x + bd.x + accd[pass][r][0];
            o4.y = xv.y + bd.y + accd[pass][r][1];
            o4.z = xv.z + bd.z + accd[pass][r][2];
            o4.w = xv.w + bd.w + accd[pass][r][3];
            *(float4*)&out[OFF_XOUT + base] = o4;
        }
    }
}

// ---------------- Kernel 3: post-proj + slice outputs ----------------
__global__ __launch_bounds__(256)
void k3_proj(const float* __restrict__ W_post, const float* __restrict__ b_post,
             float* out)
{
    const int tile = blockIdx.x, g = blockIdx.y, tid = threadIdx.x;
    const int m0 = tile * TT;
    const size_t wbase = (size_t)g * 128 * 513;

    __shared__ float sX[TT * 132];
    __shared__ float sW[DC * 64];    // [k][c]
    __shared__ float sP[TT * 132];
    __shared__ float sNrm[TT];

    for (int idx = tid; idx < TT * 32; idx += 256) {
        int t = idx >> 5, q = idx & 31;
        float4 v = *(const float4*)&out[OFF_XOUT + (size_t)(m0 + t) * 8192 + g * 128 + q * 4];
        *(float4*)&sX[t * 132 + q * 4] = v;
    }

    const int cg = tid & 15, tb = tid >> 4;

    for (int s = 0; s < 4; ++s) {
        for (int sub = 0; sub < 2; ++sub) {
            const int c0 = s * 128 + sub * 64;
            __syncthreads();
            for (int idx = tid; idx < DC * 64; idx += 256) {    // stride 513 -> scalar loads
                int k = idx >> 6, c = idx & 63;
                sW[k * 64 + c] = W_post[wbase + (size_t)k * 513 + c0 + c];
            }
            __syncthreads();

            float acc[4][4];
            #pragma unroll
            for (int r = 0; r < 4; ++r)
                #pragma unroll
                for (int c = 0; c < 4; ++c) acc[r][c] = b_post[g * 513 + c0 + cg * 4 + c];
            for (int k0 = 0; k0 < DC; k0 += 4) {
                float4 hv[4];
                #pragma unroll
                for (int r = 0; r < 4; ++r) hv[r] = *(const float4*)&sX[(tb * 4 + r) * 132 + k0];
                #pragma unroll
                for (int kk = 0; kk < 4; ++kk) {
                    float4 wv = *(const float4*)&sW[(k0 + kk) * 64 + cg * 4];
                    #pragma unroll
                    for (int r = 0; r < 4; ++r) {
                        float h = ((const float*)&hv[r])[kk];
                        acc[r][0] += h * wv.x; acc[r][1] += h * wv.y;
                        acc[r][2] += h * wv.z; acc[r][3] += h * wv.w;
                    }
                }
            }
            #pragma unroll
            for (int r = 0; r < 4; ++r)
                #pragma unroll
                for (int c = 0; c < 4; ++c)
                    sP[(tb * 4 + r) * 132 + sub * 64 + cg * 4 + c] = acc[r][c];
        }
        __syncthreads();

        if (s == 0 || s == 2) {
            int t = tid >> 2, part = tid & 3;
            float s2 = 0.f;
            #pragma unroll 8
            for (int kk = 0; kk < 32; ++kk) {
                float v = sP[t * 132 + part * 32 + kk];
                s2 += v * v;
            }
            s2 += __shfl_xor(s2, 1); s2 += __shfl_xor(s2, 2);
            if (part == 0) sNrm[t] = sqrtf(s2);
            __syncthreads();
            size_t off = (s == 0) ? OFF_KC : OFF_QN;
            for (int idx = tid; idx < TT * 32; idx += 256) {
                int t2 = idx >> 5, q = idx & 31;
                float inv = 1.f / (sNrm[t2] + 1e-6f);
                float4 v = *(const float4*)&sP[t2 * 132 + q * 4];
                v.x *= inv; v.y *= inv; v.z *= inv; v.w *= inv;
                *(float4*)&out[off + (size_t)(m0 + t2) * 8192 + g * 128 + q * 4] = v;
            }
        } else {
            size_t off = (s == 1) ? OFF_VP : OFF_VC;
            for (int idx = tid; idx < TT * 32; idx += 256) {
                int t2 = idx >> 5, q = idx & 31;
                float4 v = *(const float4*)&sP[t2 * 132 + q * 4];
                *(float4*)&out[off + (size_t)(m0 + t2) * 8192 + g * 128 + q * 4] = v;
            }
        }
    }

    // nov column (c = 512) -> w_nov
    {
        int t = tid >> 2, part = tid & 3;
        float acc = 0.f;
        #pragma unroll 8
        for (int kk = 0; kk < 32; ++kk) {
            int k = part * 32 + kk;
            acc += sX[t * 132 + k] * W_post[wbase + (size_t)k * 513 + 512];
        }
        acc += __shfl_xor(acc, 1); acc += __shfl_xor(acc, 2);
        if (part == 0) {
            float nv = acc + b_post[g * 513 + 512];
            out[OFF_WN + (size_t)(m0 + t) * 64 + g] = 1.f / (1.f + expf(-nv));
        }
    }
}

extern "C" void kernel_launch(void* const* d_in, const int* in_sizes, int n_in,
                              void* d_out, int out_size, void* d_ws, size_t ws_size,
                              hipStream_t stream) {
    const float* x_col      = (const float*)d_in[0];
    const float* z_hat_prev = (const float*)d_in[1];
    const float* gamma      = (const float*)d_in[2];
    const float* beta       = (const float*)d_in[3];
    const float* W_up       = (const float*)d_in[4];
    const float* b_up       = (const float*)d_in[5];
    const float* W_down     = (const float*)d_in[6];
    const float* b_down     = (const float*)d_in[7];
    const float* W_post     = (const float*)d_in[8];
    const float* b_post     = (const float*)d_in[9];
    const float* W_enc      = (const float*)d_in[10];
    const float* b_enc      = (const float*)d_in[11];
    const float* W_pred     = (const float*)d_in[12];
    const float* b_pred     = (const float*)d_in[13];
    const float* W_gain     = (const float*)d_in[14];
    const float* b_gain     = (const float*)d_in[15];
    float* out = (float*)d_out;

    dim3 grid(NTILE, NG);
    k1_encode_ln<<<grid, 256, 0, stream>>>(x_col, z_hat_prev, gamma, beta,
                                           W_enc, b_enc, W_pred, b_pred,
                                           W_gain, b_gain, out);
    k2_mlp<<<grid, 256, 0, stream>>>(x_col, W_up, b_up, W_down, b_down, out);
    k3_proj<<<grid, 256, 0, stream>>>(W_post, b_post, out);
}

// Round 2
// 500.407 us; speedup vs baseline: 3.2708x; 3.2708x over previous
//
#include <hip/hip_runtime.h>

typedef unsigned short u16;
typedef __attribute__((ext_vector_type(4))) unsigned short u16x4;
typedef __attribute__((ext_vector_type(8))) short short8;
typedef __attribute__((ext_vector_type(16))) float f32x16;

#define MFMA(a,b,c) __builtin_amdgcn_mfma_f32_32x32x16_bf16((a),(b),(c),0,0,0)

// ---- output offsets (floats), reference return order ----
static constexpr size_t OFF_XOUT = 0;
static constexpr size_t OFF_Z    = 16777216;
static constexpr size_t OFF_ZHAT = 20971520;
static constexpr size_t OFF_SUR  = 25165824;
static constexpr size_t OFF_KC   = 25296896;
static constexpr size_t OFF_VP   = 42074112;
static constexpr size_t OFF_GATE = 58851328;
static constexpr size_t OFF_QN   = 58982400;
static constexpr size_t OFF_VC   = 75759616;
static constexpr size_t OFF_WN   = 92536832;
static constexpr size_t OFF_S5   = 92667904;

// ---- workspace offsets (u16 elements): transposed bf16 weights ----
static constexpr size_t WUP_T = 0;          // [G][512][128]
static constexpr size_t WDN_T = 4194304;    // [G][128][512]
static constexpr size_t WPO_T = 8388608;    // [G][513][128]
static constexpr size_t WEN_T = 12591104;   // [G][32][128]
static constexpr size_t WGN_T = 12853248;   // [G][128][32]
static constexpr size_t WPR_T = 13115392;   // [G][32][32]

__device__ __forceinline__ u16 f2b(float f) {
    unsigned u = __float_as_uint(f);
    unsigned r = (u + 0x7FFFu + ((u >> 16) & 1u)) >> 16;
    return (u16)r;
}
__device__ __forceinline__ float b2f(u16 b) {
    return __uint_as_float(((unsigned)b) << 16);
}
// swizzles for [R][128]bf16 (256B rows) and [R][32]bf16 (64B rows)
__device__ __forceinline__ int swz256(int row, int b) {
    return row * 256 + (b ^ ((row & 7) << 4) ^ (((row >> 3) & 1) << 7));
}
__device__ __forceinline__ int swz64(int row, int b) {
    return row * 64 + (b ^ ((row & 3) << 4));
}
// A/B fragment loads for mfma_f32_32x32x16_bf16: lane holds 8 contiguous k,
// row/col = lane&31, k-half = lane>>5.
__device__ __forceinline__ short8 fragLd256(const u16* s, int row, int ks) {
    int b = ks * 32 + ((threadIdx.x >> 5) & 1) * 16;
    return *(const short8*)((const char*)s + swz256(row, b));
}
__device__ __forceinline__ short8 fragLd64(const u16* s, int row, int ks) {
    int b = ks * 32 + ((threadIdx.x >> 5) & 1) * 16;
    return *(const short8*)((const char*)s + swz64(row, b));
}
__device__ __forceinline__ float tanh_f(float x) {
    float xc = fminf(fmaxf(x, -15.f), 15.f);
    float e = __expf(2.f * xc);
    return __fdividef(e - 1.f, e + 1.f);
}
__device__ __forceinline__ float gelu_f(float u) {
    float y = 0.7978845608f * (u + 0.044715f * u * u * u);
    return 0.5f * u * (1.f + tanh_f(y));
}

// ---------------- transpose + f32->bf16 convert: src[G][K][C] -> dst[G][C][K] ----------------
__global__ __launch_bounds__(256)
void kconv(const float* __restrict__ src, u16* __restrict__ dst, int K, int C)
{
    const int g = blockIdx.z;
    const int k0 = blockIdx.y * 64, c0 = blockIdx.x * 64;
    __shared__ float sT[64][65];
    const float* s = src + (size_t)g * K * C;
    u16* d = dst + (size_t)g * K * C;
    for (int e = threadIdx.x; e < 64 * 64; e += 256) {
        int kk = e >> 6, cc = e & 63;
        if (k0 + kk < K && c0 + cc < C)
            sT[kk][cc] = s[(size_t)(k0 + kk) * C + c0 + cc];
    }
    __syncthreads();
    for (int e = threadIdx.x; e < 64 * 64; e += 256) {
        int cc = e >> 6, kk = e & 63;
        if (k0 + kk < K && c0 + cc < C)
            d[(size_t)(c0 + cc) * K + k0 + kk] = f2b(sT[kk][cc]);
    }
}

// ---------------- K1: encode + surprise + pred + gain + LN -> h ----------------
__global__ __launch_bounds__(256)
void k1_encode(const float* __restrict__ x_col,
               const float* __restrict__ z_hat_prev,
               const float* __restrict__ gamma,
               const float* __restrict__ beta,
               const float* __restrict__ b_enc,
               const float* __restrict__ b_pred,
               const float* __restrict__ b_gain,
               const u16* __restrict__ ws,
               float* __restrict__ out)
{
    const int tile = blockIdx.x, g = blockIdx.y;
    const int m0 = tile * 128;
    const int tid = threadIdx.x, lane = tid & 63;
    const int w = tid >> 6;
    const int l31 = lane & 31, lh = lane >> 5;

    __shared__ u16 sX[128 * 128];
    __shared__ u16 sD[128 * 32];
    __shared__ u16 sZ[128 * 32];
    __shared__ u16 sWe[32 * 128];
    __shared__ u16 sWg[128 * 32];
    __shared__ u16 sWp[32 * 32];
    __shared__ float sMu[128], sRstd[128];

    // stage x -> bf16 swizzled
    for (int idx = tid; idx < 128 * 32; idx += 256) {
        int row = idx >> 5, q = idx & 31;
        float4 v = *(const float4*)&x_col[(size_t)(m0 + row) * 8192 + g * 128 + q * 4];
        u16x4 b; b.x = f2b(v.x); b.y = f2b(v.y); b.z = f2b(v.z); b.w = f2b(v.w);
        *(u16x4*)((char*)sX + swz256(row, q * 8)) = b;
    }
    for (int idx = tid; idx < 32 * 16; idx += 256) {
        int row = idx >> 4, slot = idx & 15;
        short8 v = *(const short8*)(ws + WEN_T + ((size_t)g * 32 + row) * 128 + slot * 8);
        *(short8*)((char*)sWe + swz256(row, slot * 16)) = v;
    }
    for (int idx = tid; idx < 128 * 4; idx += 256) {
        int row = idx >> 2, slot = idx & 3;
        short8 v = *(const short8*)(ws + WGN_T + ((size_t)g * 128 + row) * 32 + slot * 8);
        *(short8*)((char*)sWg + swz64(row, slot * 16)) = v;
    }
    for (int idx = tid; idx < 32 * 4; idx += 256) {
        int row = idx >> 2, slot = idx & 3;
        short8 v = *(const short8*)(ws + WPR_T + ((size_t)g * 32 + row) * 32 + slot * 8);
        *(short8*)((char*)sWp + swz64(row, slot * 16)) = v;
    }
    __syncthreads();

    // LN stats (2 threads per row)
    {
        int row = tid >> 1, half = tid & 1;
        float s1 = 0.f, s2 = 0.f;
        #pragma unroll
        for (int i = 0; i < 8; ++i) {
            short8 v = *(const short8*)((const char*)sX + swz256(row, (half * 64 + i * 8) * 2));
            #pragma unroll
            for (int j = 0; j < 8; ++j) { float x = b2f((u16)v[j]); s1 += x; s2 += x * x; }
        }
        s1 += __shfl_xor(s1, 1); s2 += __shfl_xor(s2, 1);
        if (half == 0) {
            float mu = s1 * (1.f / 128.f);
            float var = s2 * (1.f / 128.f) - mu * mu;
            sMu[row] = mu; sRstd[row] = rsqrtf(var + 1e-5f);
        }
    }

    // enc GEMM: z = x @ W_enc  (rows 32w.., cols 0..31)
    f32x16 zacc = (f32x16)0.f;
    #pragma unroll
    for (int ks = 0; ks < 8; ++ks) {
        short8 a = fragLd256(sX, 32 * w + l31, ks);
        short8 b = fragLd256(sWe, l31, ks);
        zacc = MFMA(a, b, zacc);
    }
    float benc = b_enc[g * 32 + l31];
    #pragma unroll
    for (int r = 0; r < 16; ++r) {
        float zv = zacc[r] + benc;
        int row = 32 * w + (r & 3) + 8 * (r >> 2) + 4 * lh;
        size_t zoff = (size_t)(m0 + row) * 2048 + g * 32 + l31;
        out[OFF_Z + zoff] = zv;
        float d = zv - z_hat_prev[zoff];
        *(u16*)((char*)sD + swz64(row, l31 * 2)) = f2b(d);
        *(u16*)((char*)sZ + swz64(row, l31 * 2)) = f2b(zv);
        float ss = d * d;
        ss += __shfl_xor(ss, 1); ss += __shfl_xor(ss, 2); ss += __shfl_xor(ss, 4);
        ss += __shfl_xor(ss, 8); ss += __shfl_xor(ss, 16);
        if (l31 == 0) {
            float sur = sqrtf(ss);
            size_t p = (size_t)(m0 + row) * 64 + g;
            out[OFF_SUR + p] = sur;
            out[OFF_S5 + p] = sur;
            out[OFF_GATE + p] = fminf(fmaxf(sur, 0.f), 1.f);
        }
    }
    __syncthreads();

    // pred GEMM: z_hat = z @ W_pred
    f32x16 pacc = (f32x16)0.f;
    #pragma unroll
    for (int ks = 0; ks < 2; ++ks) {
        short8 a = fragLd64(sZ, 32 * w + l31, ks);
        short8 b = fragLd64(sWp, l31, ks);
        pacc = MFMA(a, b, pacc);
    }
    float bpred = b_pred[g * 32 + l31];
    #pragma unroll
    for (int r = 0; r < 16; ++r) {
        int row = 32 * w + (r & 3) + 8 * (r >> 2) + 4 * lh;
        out[OFF_ZHAT + (size_t)(m0 + row) * 2048 + g * 32 + l31] = pacc[r] + bpred;
    }

    // gain GEMM: delta @ W_gain (rows 32w.., cols 0..127), then LN apply -> h
    f32x16 gacc[4];
    #pragma unroll
    for (int c = 0; c < 4; ++c) gacc[c] = (f32x16)0.f;
    #pragma unroll
    for (int ks = 0; ks < 2; ++ks) {
        short8 a = fragLd64(sD, 32 * w + l31, ks);
        #pragma unroll
        for (int c = 0; c < 4; ++c) {
            short8 b = fragLd64(sWg, 32 * c + l31, ks);
            gacc[c] = MFMA(a, b, gacc[c]);
        }
    }
    #pragma unroll
    for (int c = 0; c < 4; ++c) {
        int col = 32 * c + l31;
        float bg = b_gain[g * 128 + col];
        float gam = gamma[g * 128 + col];
        float bet = beta[g * 128 + col];
        #pragma unroll
        for (int r = 0; r < 16; ++r) {
            int row = 32 * w + (r & 3) + 8 * (r >> 2) + 4 * lh;
            float gain = 1.f + 0.1f * tanh_f(gacc[c][r] + bg);
            float xv = b2f(*(const u16*)((const char*)sX + swz256(row, col * 2)));
            float h = ((xv - sMu[row]) * sRstd[row] * gam + bet) * gain;
            out[OFF_XOUT + (size_t)(m0 + row) * 8192 + g * 128 + col] = h;
        }
    }
}

// ---------------- K2: MLP up+gelu+down + residual ----------------
__global__ __launch_bounds__(256)
void k2_mlp(const float* __restrict__ x_col,
            const float* __restrict__ b_up,
            const float* __restrict__ b_down,
            const u16* __restrict__ ws,
            float* __restrict__ out)
{
    const int tile = blockIdx.x, g = blockIdx.y;
    const int m0 = tile * 128;
    const int tid = threadIdx.x, lane = tid & 63;
    const int wr = (tid >> 7) & 1, wc = (tid >> 6) & 1;
    const int l31 = lane & 31, lh = lane >> 5;

    __shared__ u16 sH[128 * 128];
    __shared__ u16 sW[128 * 128];
    __shared__ u16 sU[128 * 128];

    // stage h (f32, from out[XOUT]) -> bf16 swizzled
    for (int idx = tid; idx < 128 * 32; idx += 256) {
        int row = idx >> 5, q = idx & 31;
        float4 v = *(const float4*)&out[OFF_XOUT + (size_t)(m0 + row) * 8192 + g * 128 + q * 4];
        u16x4 b; b.x = f2b(v.x); b.y = f2b(v.y); b.z = f2b(v.z); b.w = f2b(v.w);
        *(u16x4*)((char*)sH + swz256(row, q * 8)) = b;
    }

    f32x16 dacc[2][2];
    #pragma unroll
    for (int f = 0; f < 2; ++f)
        #pragma unroll
        for (int c = 0; c < 2; ++c) dacc[f][c] = (f32x16)0.f;

    const u16* wUp = ws + WUP_T + (size_t)g * 65536;
    const u16* wDn = ws + WDN_T + (size_t)g * 65536;

    for (int ch = 0; ch < 4; ++ch) {
        const int c0 = ch * 128;
        __syncthreads();
        for (int idx = tid; idx < 128 * 16; idx += 256) {   // W_upT chunk [c][k]
            int row = idx >> 4, slot = idx & 15;
            short8 v = *(const short8*)(wUp + (size_t)(c0 + row) * 128 + slot * 8);
            *(short8*)((char*)sW + swz256(row, slot * 16)) = v;
        }
        __syncthreads();

        f32x16 uacc[2][2];
        #pragma unroll
        for (int f = 0; f < 2; ++f)
            #pragma unroll
            for (int c = 0; c < 2; ++c) uacc[f][c] = (f32x16)0.f;
        #pragma unroll
        for (int ks = 0; ks < 8; ++ks) {
            short8 a0 = fragLd256(sH, 64 * wr + l31, ks);
            short8 a1 = fragLd256(sH, 64 * wr + 32 + l31, ks);
            short8 b0 = fragLd256(sW, 64 * wc + l31, ks);
            short8 b1 = fragLd256(sW, 64 * wc + 32 + l31, ks);
            uacc[0][0] = MFMA(a0, b0, uacc[0][0]);
            uacc[0][1] = MFMA(a0, b1, uacc[0][1]);
            uacc[1][0] = MFMA(a1, b0, uacc[1][0]);
            uacc[1][1] = MFMA(a1, b1, uacc[1][1]);
        }
        #pragma unroll
        for (int f = 0; f < 2; ++f)
            #pragma unroll
            for (int c = 0; c < 2; ++c) {
                float bup = b_up[(size_t)g * 512 + c0 + 64 * wc + 32 * c + l31];
                int colB = (64 * wc + 32 * c + l31) * 2;
                #pragma unroll
                for (int r = 0; r < 16; ++r) {
                    int row = 64 * wr + 32 * f + (r & 3) + 8 * (r >> 2) + 4 * lh;
                    float gel = gelu_f(uacc[f][c][r] + bup);
                    *(u16*)((char*)sU + swz256(row, colB)) = f2b(gel);
                }
            }
        __syncthreads();
        for (int idx = tid; idx < 128 * 16; idx += 256) {   // W_downT chunk [j][c0..c0+127]
            int row = idx >> 4, slot = idx & 15;
            short8 v = *(const short8*)(wDn + (size_t)row * 512 + c0 + slot * 8);
            *(short8*)((char*)sW + swz256(row, slot * 16)) = v;
        }
        __syncthreads();
        #pragma unroll
        for (int ks = 0; ks < 8; ++ks) {
            short8 a0 = fragLd256(sU, 64 * wr + l31, ks);
            short8 a1 = fragLd256(sU, 64 * wr + 32 + l31, ks);
            short8 b0 = fragLd256(sW, 64 * wc + l31, ks);
            short8 b1 = fragLd256(sW, 64 * wc + 32 + l31, ks);
            dacc[0][0] = MFMA(a0, b0, dacc[0][0]);
            dacc[0][1] = MFMA(a0, b1, dacc[0][1]);
            dacc[1][0] = MFMA(a1, b0, dacc[1][0]);
            dacc[1][1] = MFMA(a1, b1, dacc[1][1]);
        }
    }

    // epilogue: x_out = x + b_down + mlp
    #pragma unroll
    for (int f = 0; f < 2; ++f)
        #pragma unroll
        for (int c = 0; c < 2; ++c) {
            int j = 64 * wc + 32 * c + l31;
            float bd = b_down[g * 128 + j];
            #pragma unroll
            for (int r = 0; r < 16; ++r) {
                int row = 64 * wr + 32 * f + (r & 3) + 8 * (r >> 2) + 4 * lh;
                size_t base = (size_t)(m0 + row) * 8192 + g * 128 + j;
                out[OFF_XOUT + base] = x_col[base] + bd + dacc[f][c][r];
            }
        }
}

// ---------------- K3: post-proj + slice outputs ----------------
__global__ __launch_bounds__(256)
void k3_proj(const float* __restrict__ b_post,
             const u16* __restrict__ ws,
             float* __restrict__ out)
{
    const int tile = blockIdx.x, g = blockIdx.y;
    const int m0 = tile * 128;
    const int tid = threadIdx.x, lane = tid & 63;
    const int wr = (tid >> 7) & 1, wc = (tid >> 6) & 1;
    const int l31 = lane & 31, lh = lane >> 5;

    __shared__ u16 sX[128 * 128];
    __shared__ u16 sW[128 * 128];
    __shared__ u16 sP[128 * 128];
    __shared__ float sNrm[128];
    __shared__ float sNov[128];

    const u16* wPo = ws + WPO_T + (size_t)g * 65664;

    for (int idx = tid; idx < 128 * 32; idx += 256) {
        int row = idx >> 5, q = idx & 31;
        float4 v = *(const float4*)&out[OFF_XOUT + (size_t)(m0 + row) * 8192 + g * 128 + q * 4];
        u16x4 b; b.x = f2b(v.x); b.y = f2b(v.y); b.z = f2b(v.z); b.w = f2b(v.w);
        *(u16x4*)((char*)sX + swz256(row, q * 8)) = b;
    }
    if (tid < 128) sNov[tid] = b2f(wPo[(size_t)512 * 128 + tid]);

    for (int s = 0; s < 4; ++s) {
        __syncthreads();
        for (int idx = tid; idx < 128 * 16; idx += 256) {   // W_postT slice [c][k]
            int row = idx >> 4, slot = idx & 15;
            short8 v = *(const short8*)(wPo + (size_t)(s * 128 + row) * 128 + slot * 8);
            *(short8*)((char*)sW + swz256(row, slot * 16)) = v;
        }
        __syncthreads();

        f32x16 acc[2][2];
        #pragma unroll
        for (int f = 0; f < 2; ++f)
            #pragma unroll
            for (int c = 0; c < 2; ++c) acc[f][c] = (f32x16)0.f;
        #pragma unroll
        for (int ks = 0; ks < 8; ++ks) {
            short8 a0 = fragLd256(sX, 64 * wr + l31, ks);
            short8 a1 = fragLd256(sX, 64 * wr + 32 + l31, ks);
            short8 b0 = fragLd256(sW, 64 * wc + l31, ks);
            short8 b1 = fragLd256(sW, 64 * wc + 32 + l31, ks);
            acc[0][0] = MFMA(a0, b0, acc[0][0]);
            acc[0][1] = MFMA(a0, b1, acc[0][1]);
            acc[1][0] = MFMA(a1, b0, acc[1][0]);
            acc[1][1] = MFMA(a1, b1, acc[1][1]);
        }
        #pragma unroll
        for (int f = 0; f < 2; ++f)
            #pragma unroll
            for (int c = 0; c < 2; ++c) {
                float bp = b_post[g * 513 + s * 128 + 64 * wc + 32 * c + l31];
                int colB = (64 * wc + 32 * c + l31) * 2;
                #pragma unroll
                for (int r = 0; r < 16; ++r) {
                    int row = 64 * wr + 32 * f + (r & 3) + 8 * (r >> 2) + 4 * lh;
                    *(u16*)((char*)sP + swz256(row, colB)) = f2b(acc[f][c][r] + bp);
                }
            }
        __syncthreads();

        const bool nrm = (s == 0 || s == 2);
        if (nrm) {
            int row = tid >> 1, half = tid & 1;
            float ss = 0.f;
            #pragma unroll
            for (int i = 0; i < 8; ++i) {
                short8 v = *(const short8*)((const char*)sP + swz256(row, (half * 64 + i * 8) * 2));
                #pragma unroll
                for (int j = 0; j < 8; ++j) { float x = b2f((u16)v[j]); ss += x * x; }
            }
            ss += __shfl_xor(ss, 1);
            if (half == 0) sNrm[row] = sqrtf(ss);
            __syncthreads();
        }
        size_t off = (s == 0) ? OFF_KC : (s == 1) ? OFF_VP : (s == 2) ? OFF_QN : OFF_VC;
        for (int idx = tid; idx < 128 * 16; idx += 256) {
            int row = idx >> 4, slot = idx & 15;
            float inv = nrm ? __fdividef(1.f, sNrm[row] + 1e-6f) : 1.f;
            short8 v = *(const short8*)((const char*)sP + swz256(row, slot * 16));
            float4 o0, o1;
            o0.x = b2f((u16)v[0]) * inv; o0.y = b2f((u16)v[1]) * inv;
            o0.z = b2f((u16)v[2]) * inv; o0.w = b2f((u16)v[3]) * inv;
            o1.x = b2f((u16)v[4]) * inv; o1.y = b2f((u16)v[5]) * inv;
            o1.z = b2f((u16)v[6]) * inv; o1.w = b2f((u16)v[7]) * inv;
            size_t base = off + (size_t)(m0 + row) * 8192 + g * 128 + slot * 8;
            *(float4*)&out[base] = o0;
            *(float4*)&out[base + 4] = o1;
        }
    }
    __syncthreads();

    // nov column -> w_nov
    {
        int row = tid >> 1, half = tid & 1;
        float accn = 0.f;
        #pragma unroll
        for (int i = 0; i < 8; ++i) {
            short8 v = *(const short8*)((const char*)sX + swz256(row, (half * 64 + i * 8) * 2));
            #pragma unroll
            for (int j = 0; j < 8; ++j) accn += b2f((u16)v[j]) * sNov[half * 64 + i * 8 + j];
        }
        accn += __shfl_xor(accn, 1);
        if (half == 0) {
            float nv = accn + b_post[g * 513 + 512];
            out[OFF_WN + (size_t)(m0 + row) * 64 + g] = __fdividef(1.f, 1.f + __expf(-nv));
        }
    }
}

extern "C" void kernel_launch(void* const* d_in, const int* in_sizes, int n_in,
                              void* d_out, int out_size, void* d_ws, size_t ws_size,
                              hipStream_t stream) {
    const float* x_col      = (const float*)d_in[0];
    const float* z_hat_prev = (const float*)d_in[1];
    const float* gamma      = (const float*)d_in[2];
    const float* beta       = (const float*)d_in[3];
    const float* W_up       = (const float*)d_in[4];
    const float* b_up       = (const float*)d_in[5];
    const float* W_down     = (const float*)d_in[6];
    const float* b_down     = (const float*)d_in[7];
    const float* W_post     = (const float*)d_in[8];
    const float* b_post     = (const float*)d_in[9];
    const float* W_enc      = (const float*)d_in[10];
    const float* b_enc      = (const float*)d_in[11];
    const float* W_pred     = (const float*)d_in[12];
    const float* b_pred     = (const float*)d_in[13];
    const float* W_gain     = (const float*)d_in[14];
    const float* b_gain     = (const float*)d_in[15];
    float* out = (float*)d_out;
    u16* ws = (u16*)d_ws;

    kconv<<<dim3(8, 2, 64), 256, 0, stream>>>(W_up,   ws + WUP_T, 128, 512);
    kconv<<<dim3(2, 8, 64), 256, 0, stream>>>(W_down, ws + WDN_T, 512, 128);
    kconv<<<dim3(9, 2, 64), 256, 0, stream>>>(W_post, ws + WPO_T, 128, 513);
    kconv<<<dim3(1, 2, 64), 256, 0, stream>>>(W_enc,  ws + WEN_T, 128, 32);
    kconv<<<dim3(2, 1, 64), 256, 0, stream>>>(W_gain, ws + WGN_T, 32, 128);
    kconv<<<dim3(1, 1, 64), 256, 0, stream>>>(W_pred, ws + WPR_T, 32, 32);

    dim3 grid(16, 64);
    k1_encode<<<grid, 256, 0, stream>>>(x_col, z_hat_prev, gamma, beta,
                                        b_enc, b_pred, b_gain, ws, out);
    k2_mlp<<<grid, 256, 0, stream>>>(x_col, b_up, b_down, ws, out);
    k3_proj<<<grid, 256, 0, stream>>>(b_post, ws, out);
}

// Round 4
// 486.368 us; speedup vs baseline: 3.3652x; 1.0289x over previous
//
#include <hip/hip_runtime.h>

typedef unsigned short u16;
typedef __attribute__((ext_vector_type(4))) unsigned short u16x4;
typedef __attribute__((ext_vector_type(8))) short short8;
typedef __attribute__((ext_vector_type(16))) float f32x16;

#define MFMA(a,b,c) __builtin_amdgcn_mfma_f32_32x32x16_bf16((a),(b),(c),0,0,0)

// ---- output offsets (floats), reference return order ----
static constexpr size_t OFF_XOUT = 0;
static constexpr size_t OFF_Z    = 16777216;
static constexpr size_t OFF_ZHAT = 20971520;
static constexpr size_t OFF_SUR  = 25165824;
static constexpr size_t OFF_KC   = 25296896;
static constexpr size_t OFF_VP   = 42074112;
static constexpr size_t OFF_GATE = 58851328;
static constexpr size_t OFF_QN   = 58982400;
static constexpr size_t OFF_VC   = 75759616;
static constexpr size_t OFF_WN   = 92536832;
static constexpr size_t OFF_S5   = 92667904;

// ---- workspace offsets (u16 elements): transposed bf16 weights ----
static constexpr size_t WUP_T = 0;          // [G][512][128]
static constexpr size_t WDN_T = 4194304;    // [G][128][512]
static constexpr size_t WPO_T = 8388608;    // [G][513][128]
static constexpr size_t WEN_T = 12591104;   // [G][32][128]
static constexpr size_t WGN_T = 12853248;   // [G][128][32]
static constexpr size_t WPR_T = 13115392;   // [G][32][32]

__device__ __forceinline__ u16 f2b(float f) {
    unsigned u = __float_as_uint(f);
    unsigned r = (u + 0x7FFFu + ((u >> 16) & 1u)) >> 16;
    return (u16)r;
}
__device__ __forceinline__ float b2f(u16 b) {
    return __uint_as_float(((unsigned)b) << 16);
}
// swizzles for [R][128]bf16 (256B rows) and [R][32]bf16 (64B rows)
__device__ __forceinline__ int swz256(int row, int b) {
    return row * 256 + (b ^ ((row & 7) << 4) ^ (((row >> 3) & 1) << 7));
}
__device__ __forceinline__ int swz64(int row, int b) {
    return row * 64 + (b ^ ((row & 3) << 4));
}
// A/B fragment loads for mfma_f32_32x32x16_bf16: lane holds 8 contiguous k,
// row/col = lane&31, k-half = lane>>5.
__device__ __forceinline__ short8 fragLd256(const u16* s, int row, int ks) {
    int b = ks * 32 + ((threadIdx.x >> 5) & 1) * 16;
    return *(const short8*)((const char*)s + swz256(row, b));
}
__device__ __forceinline__ short8 fragLd64(const u16* s, int row, int ks) {
    int b = ks * 32 + ((threadIdx.x >> 5) & 1) * 16;
    return *(const short8*)((const char*)s + swz64(row, b));
}
__device__ __forceinline__ float tanh_f(float x) {
    float xc = fminf(fmaxf(x, -15.f), 15.f);
    float e = __expf(2.f * xc);
    return __fdividef(e - 1.f, e + 1.f);
}
__device__ __forceinline__ float gelu_f(float u) {
    float y = 0.7978845608f * (u + 0.044715f * u * u * u);
    return 0.5f * u * (1.f + tanh_f(y));
}

// ---------------- fused transpose+convert for all six weights ----------------
// src[G][K][C] f32 -> dst[G][C][K] bf16
__global__ __launch_bounds__(256)
void kconv_all(const float* __restrict__ W_up, const float* __restrict__ W_down,
               const float* __restrict__ W_post, const float* __restrict__ W_enc,
               const float* __restrict__ W_gain, const float* __restrict__ W_pred,
               u16* __restrict__ ws)
{
    int b = blockIdx.x;
    const float* src; u16* dst; int K, C, bx;
    if (b < 1024)      { src = W_up;   dst = ws + WUP_T; K = 128; C = 512; bx = 8; }
    else if (b < 2048) { b -= 1024; src = W_down; dst = ws + WDN_T; K = 512; C = 128; bx = 2; }
    else if (b < 3200) { b -= 2048; src = W_post; dst = ws + WPO_T; K = 128; C = 513; bx = 9; }
    else if (b < 3328) { b -= 3200; src = W_enc;  dst = ws + WEN_T; K = 128; C = 32;  bx = 1; }
    else if (b < 3456) { b -= 3328; src = W_gain; dst = ws + WGN_T; K = 32;  C = 128; bx = 2; }
    else               { b -= 3456; src = W_pred; dst = ws + WPR_T; K = 32;  C = 32;  bx = 1; }
    const int by = (K + 63) >> 6;
    const int nb = bx * by;
    const int g = b / nb, r = b % nb;
    const int c0 = (r % bx) * 64, k0 = (r / bx) * 64;

    __shared__ float sT[64][65];
    const float* s = src + (size_t)g * K * C;
    u16* d = dst + (size_t)g * K * C;
    for (int e = threadIdx.x; e < 64 * 64; e += 256) {
        int kk = e >> 6, cc = e & 63;
        if (k0 + kk < K && c0 + cc < C)
            sT[kk][cc] = s[(size_t)(k0 + kk) * C + c0 + cc];
    }
    __syncthreads();
    for (int e = threadIdx.x; e < 64 * 64; e += 256) {
        int cc = e >> 6, kk = e & 63;
        if (k0 + kk < K && c0 + cc < C)
            d[(size_t)(c0 + cc) * K + k0 + kk] = f2b(sT[kk][cc]);
    }
}

// ---------------- fully fused main kernel ----------------
__global__ __launch_bounds__(256)
void kfused(const float* __restrict__ x_col,
            const float* __restrict__ z_hat_prev,
            const float* __restrict__ gamma,
            const float* __restrict__ beta,
            const float* __restrict__ b_enc,
            const float* __restrict__ b_pred,
            const float* __restrict__ b_gain,
            const float* __restrict__ b_up,
            const float* __restrict__ b_down,
            const float* __restrict__ b_post,
            const u16* __restrict__ ws,
            float* __restrict__ out)
{
    // XCD-aware mapping: blocks with the same XCD residue (bid&7) cover a
    // contiguous set of 8 groups -> weight working set ~3.1MB fits per-XCD L2.
    const int bid = blockIdx.x;
    const int xc = bid & 7, j = bid >> 3;
    const int g = xc * 8 + (j >> 4);
    const int tile = j & 15;
    const int m0 = tile * 128;

    const int tid = threadIdx.x, lane = tid & 63;
    const int w4 = tid >> 6;                 // wave id 0..3
    const int wr = (tid >> 7) & 1, wc = (tid >> 6) & 1;
    const int l31 = lane & 31, lh = lane >> 5;

    __shared__ u16 sX[128 * 128];   // x bf16 (phase A + residual)
    __shared__ u16 sH[128 * 128];   // h (A->B), then x_out bf16 (B->C)
    __shared__ u16 sW[128 * 128];   // weight staging (all phases)
    __shared__ u16 sU[128 * 128];   // A: D/Z subregions; B: gelu out; C: sP
    __shared__ float sMu[128], sRstd[128], sNrm[128], sNov[128];

    const u16* wPo = ws + WPO_T + (size_t)g * 65664;

    // ---- phase A staging ----
    // Small weights packed INSIDE sW (u16-element offsets; x2 = byte offsets):
    //   sWe bytes [0, 8192)  : Wenc^T [32][128] swz256
    //   sWg bytes [16384,24576): Wgain^T [128][32] swz64
    //   sWp bytes [24576,26624): Wpred^T [32][32] swz64
    // (round-3 bug: offsets 16384/24576 ELEMENTS overflowed sW's 16384
    //  elements into the neighboring LDS array, clobbering staged x.)
    u16* sWe = sW;
    u16* sWg = sW + 8192;
    u16* sWp = sW + 12288;
    u16* sD  = sU;               // delta [128][32] swz64, bytes [0,8192)
    u16* sZ  = sU + 4096;        // z     [128][32] swz64, bytes [8192,16384)

    for (int idx = tid; idx < 128 * 32; idx += 256) {
        int row = idx >> 5, q = idx & 31;
        float4 v = *(const float4*)&x_col[(size_t)(m0 + row) * 8192 + g * 128 + q * 4];
        u16x4 bv; bv.x = f2b(v.x); bv.y = f2b(v.y); bv.z = f2b(v.z); bv.w = f2b(v.w);
        *(u16x4*)((char*)sX + swz256(row, q * 8)) = bv;
    }
    for (int idx = tid; idx < 32 * 16; idx += 256) {
        int row = idx >> 4, slot = idx & 15;
        short8 v = *(const short8*)(ws + WEN_T + ((size_t)g * 32 + row) * 128 + slot * 8);
        *(short8*)((char*)sWe + swz256(row, slot * 16)) = v;
    }
    for (int idx = tid; idx < 128 * 4; idx += 256) {
        int row = idx >> 2, slot = idx & 3;
        short8 v = *(const short8*)(ws + WGN_T + ((size_t)g * 128 + row) * 32 + slot * 8);
        *(short8*)((char*)sWg + swz64(row, slot * 16)) = v;
    }
    for (int idx = tid; idx < 32 * 4; idx += 256) {
        int row = idx >> 2, slot = idx & 3;
        short8 v = *(const short8*)(ws + WPR_T + ((size_t)g * 32 + row) * 32 + slot * 8);
        *(short8*)((char*)sWp + swz64(row, slot * 16)) = v;
    }
    if (tid < 128) sNov[tid] = b2f(wPo[(size_t)512 * 128 + tid]);
    __syncthreads();

    // LN stats (2 threads per row)
    {
        int row = tid >> 1, half = tid & 1;
        float s1 = 0.f, s2 = 0.f;
        #pragma unroll
        for (int i = 0; i < 8; ++i) {
            short8 v = *(const short8*)((const char*)sX + swz256(row, (half * 64 + i * 8) * 2));
            #pragma unroll
            for (int jj = 0; jj < 8; ++jj) { float x = b2f((u16)v[jj]); s1 += x; s2 += x * x; }
        }
        s1 += __shfl_xor(s1, 1); s2 += __shfl_xor(s2, 1);
        if (half == 0) {
            float mu = s1 * (1.f / 128.f);
            float var = s2 * (1.f / 128.f) - mu * mu;
            sMu[row] = mu; sRstd[row] = rsqrtf(var + 1e-5f);
        }
    }

    // enc GEMM: z = x @ W_enc (rows 32*w4.., cols 0..31)
    f32x16 zacc = (f32x16)0.f;
    #pragma unroll
    for (int ks = 0; ks < 8; ++ks) {
        short8 a = fragLd256(sX, 32 * w4 + l31, ks);
        short8 b = fragLd256(sWe, l31, ks);
        zacc = MFMA(a, b, zacc);
    }
    {
        float benc = b_enc[g * 32 + l31];
        #pragma unroll
        for (int r = 0; r < 16; ++r) {
            float zv = zacc[r] + benc;
            int row = 32 * w4 + (r & 3) + 8 * (r >> 2) + 4 * lh;
            size_t zoff = (size_t)(m0 + row) * 2048 + g * 32 + l31;
            out[OFF_Z + zoff] = zv;
            float d = zv - z_hat_prev[zoff];
            *(u16*)((char*)sD + swz64(row, l31 * 2)) = f2b(d);
            *(u16*)((char*)sZ + swz64(row, l31 * 2)) = f2b(zv);
            float ss = d * d;
            ss += __shfl_xor(ss, 1); ss += __shfl_xor(ss, 2); ss += __shfl_xor(ss, 4);
            ss += __shfl_xor(ss, 8); ss += __shfl_xor(ss, 16);
            if (l31 == 0) {
                float sur = sqrtf(ss);
                size_t p = (size_t)(m0 + row) * 64 + g;
                out[OFF_SUR + p] = sur;
                out[OFF_S5 + p] = sur;
                out[OFF_GATE + p] = fminf(fmaxf(sur, 0.f), 1.f);
            }
        }
    }
    __syncthreads();

    // pred GEMM: z_hat = z @ W_pred
    {
        f32x16 pacc = (f32x16)0.f;
        #pragma unroll
        for (int ks = 0; ks < 2; ++ks) {
            short8 a = fragLd64(sZ, 32 * w4 + l31, ks);
            short8 b = fragLd64(sWp, l31, ks);
            pacc = MFMA(a, b, pacc);
        }
        float bpred = b_pred[g * 32 + l31];
        #pragma unroll
        for (int r = 0; r < 16; ++r) {
            int row = 32 * w4 + (r & 3) + 8 * (r >> 2) + 4 * lh;
            out[OFF_ZHAT + (size_t)(m0 + row) * 2048 + g * 32 + l31] = pacc[r] + bpred;
        }
    }

    // gain GEMM: delta @ W_gain, then LN apply -> h into sH (LDS only)
    {
        f32x16 gacc[4];
        #pragma unroll
        for (int c = 0; c < 4; ++c) gacc[c] = (f32x16)0.f;
        #pragma unroll
        for (int ks = 0; ks < 2; ++ks) {
            short8 a = fragLd64(sD, 32 * w4 + l31, ks);
            #pragma unroll
            for (int c = 0; c < 4; ++c) {
                short8 b = fragLd64(sWg, 32 * c + l31, ks);
                gacc[c] = MFMA(a, b, gacc[c]);
            }
        }
        #pragma unroll
        for (int c = 0; c < 4; ++c) {
            int col = 32 * c + l31;
            float bg = b_gain[g * 128 + col];
            float gam = gamma[g * 128 + col];
            float bet = beta[g * 128 + col];
            #pragma unroll
            for (int r = 0; r < 16; ++r) {
                int row = 32 * w4 + (r & 3) + 8 * (r >> 2) + 4 * lh;
                float gain = 1.f + 0.1f * tanh_f(gacc[c][r] + bg);
                float xv = b2f(*(const u16*)((const char*)sX + swz256(row, col * 2)));
                float h = ((xv - sMu[row]) * sRstd[row] * gam + bet) * gain;
                *(u16*)((char*)sH + swz256(row, col * 2)) = f2b(h);
            }
        }
    }

    // ---- phase B: MLP ----
    const u16* wUp = ws + WUP_T + (size_t)g * 65536;
    const u16* wDn = ws + WDN_T + (size_t)g * 65536;

    f32x16 dacc[2][2];
    #pragma unroll
    for (int f = 0; f < 2; ++f)
        #pragma unroll
        for (int c = 0; c < 2; ++c) dacc[f][c] = (f32x16)0.f;

    for (int ch = 0; ch < 4; ++ch) {
        const int c0 = ch * 128;
        __syncthreads();
        for (int idx = tid; idx < 128 * 16; idx += 256) {   // W_upT chunk [c][k]
            int row = idx >> 4, slot = idx & 15;
            short8 v = *(const short8*)(wUp + (size_t)(c0 + row) * 128 + slot * 8);
            *(short8*)((char*)sW + swz256(row, slot * 16)) = v;
        }
        __syncthreads();

        f32x16 uacc[2][2];
        #pragma unroll
        for (int f = 0; f < 2; ++f)
            #pragma unroll
            for (int c = 0; c < 2; ++c) uacc[f][c] = (f32x16)0.f;
        #pragma unroll
        for (int ks = 0; ks < 8; ++ks) {
            short8 a0 = fragLd256(sH, 64 * wr + l31, ks);
            short8 a1 = fragLd256(sH, 64 * wr + 32 + l31, ks);
            short8 b0 = fragLd256(sW, 64 * wc + l31, ks);
            short8 b1 = fragLd256(sW, 64 * wc + 32 + l31, ks);
            uacc[0][0] = MFMA(a0, b0, uacc[0][0]);
            uacc[0][1] = MFMA(a0, b1, uacc[0][1]);
            uacc[1][0] = MFMA(a1, b0, uacc[1][0]);
            uacc[1][1] = MFMA(a1, b1, uacc[1][1]);
        }
        #pragma unroll
        for (int f = 0; f < 2; ++f)
            #pragma unroll
            for (int c = 0; c < 2; ++c) {
                float bup = b_up[(size_t)g * 512 + c0 + 64 * wc + 32 * c + l31];
                int colB = (64 * wc + 32 * c + l31) * 2;
                #pragma unroll
                for (int r = 0; r < 16; ++r) {
                    int row = 64 * wr + 32 * f + (r & 3) + 8 * (r >> 2) + 4 * lh;
                    float gel = gelu_f(uacc[f][c][r] + bup);
                    *(u16*)((char*)sU + swz256(row, colB)) = f2b(gel);
                }
            }
        __syncthreads();
        for (int idx = tid; idx < 128 * 16; idx += 256) {   // W_downT chunk [j][c-slice]
            int row = idx >> 4, slot = idx & 15;
            short8 v = *(const short8*)(wDn + (size_t)row * 512 + c0 + slot * 8);
            *(short8*)((char*)sW + swz256(row, slot * 16)) = v;
        }
        __syncthreads();
        #pragma unroll
        for (int ks = 0; ks < 8; ++ks) {
            short8 a0 = fragLd256(sU, 64 * wr + l31, ks);
            short8 a1 = fragLd256(sU, 64 * wr + 32 + l31, ks);
            short8 b0 = fragLd256(sW, 64 * wc + l31, ks);
            short8 b1 = fragLd256(sW, 64 * wc + 32 + l31, ks);
            dacc[0][0] = MFMA(a0, b0, dacc[0][0]);
            dacc[0][1] = MFMA(a0, b1, dacc[0][1]);
            dacc[1][0] = MFMA(a1, b0, dacc[1][0]);
            dacc[1][1] = MFMA(a1, b1, dacc[1][1]);
        }
    }

    // epilogue: x_out = x + b_down + mlp -> global f32 + sH bf16
    #pragma unroll
    for (int f = 0; f < 2; ++f)
        #pragma unroll
        for (int c = 0; c < 2; ++c) {
            int jc = 64 * wc + 32 * c + l31;
            float bd = b_down[g * 128 + jc];
            #pragma unroll
            for (int r = 0; r < 16; ++r) {
                int row = 64 * wr + 32 * f + (r & 3) + 8 * (r >> 2) + 4 * lh;
                size_t base = (size_t)(m0 + row) * 8192 + g * 128 + jc;
                float xo = b2f(*(const u16*)((const char*)sX + swz256(row, jc * 2)))
                           + bd + dacc[f][c][r];
                out[OFF_XOUT + base] = xo;
                *(u16*)((char*)sH + swz256(row, jc * 2)) = f2b(xo);
            }
        }

    // ---- phase C: post-proj (sH = x_out bf16, sU = sP) ----
    for (int s = 0; s < 4; ++s) {
        __syncthreads();
        for (int idx = tid; idx < 128 * 16; idx += 256) {   // W_postT slice [c][k]
            int row = idx >> 4, slot = idx & 15;
            short8 v = *(const short8*)(wPo + (size_t)(s * 128 + row) * 128 + slot * 8);
            *(short8*)((char*)sW + swz256(row, slot * 16)) = v;
        }
        __syncthreads();

        f32x16 acc[2][2];
        #pragma unroll
        for (int f = 0; f < 2; ++f)
            #pragma unroll
            for (int c = 0; c < 2; ++c) acc[f][c] = (f32x16)0.f;
        #pragma unroll
        for (int ks = 0; ks < 8; ++ks) {
            short8 a0 = fragLd256(sH, 64 * wr + l31, ks);
            short8 a1 = fragLd256(sH, 64 * wr + 32 + l31, ks);
            short8 b0 = fragLd256(sW, 64 * wc + l31, ks);
            short8 b1 = fragLd256(sW, 64 * wc + 32 + l31, ks);
            acc[0][0] = MFMA(a0, b0, acc[0][0]);
            acc[0][1] = MFMA(a0, b1, acc[0][1]);
            acc[1][0] = MFMA(a1, b0, acc[1][0]);
            acc[1][1] = MFMA(a1, b1, acc[1][1]);
        }
        #pragma unroll
        for (int f = 0; f < 2; ++f)
            #pragma unroll
            for (int c = 0; c < 2; ++c) {
                float bp = b_post[g * 513 + s * 128 + 64 * wc + 32 * c + l31];
                int colB = (64 * wc + 32 * c + l31) * 2;
                #pragma unroll
                for (int r = 0; r < 16; ++r) {
                    int row = 64 * wr + 32 * f + (r & 3) + 8 * (r >> 2) + 4 * lh;
                    *(u16*)((char*)sU + swz256(row, colB)) = f2b(acc[f][c][r] + bp);
                }
            }
        __syncthreads();

        const bool nrm = (s == 0 || s == 2);
        if (nrm) {
            int row = tid >> 1, half = tid & 1;
            float ss = 0.f;
            #pragma unroll
            for (int i = 0; i < 8; ++i) {
                short8 v = *(const short8*)((const char*)sU + swz256(row, (half * 64 + i * 8) * 2));
                #pragma unroll
                for (int jj = 0; jj < 8; ++jj) { float x = b2f((u16)v[jj]); ss += x * x; }
            }
            ss += __shfl_xor(ss, 1);
            if (half == 0) sNrm[row] = sqrtf(ss);
            __syncthreads();
        }
        size_t off = (s == 0) ? OFF_KC : (s == 1) ? OFF_VP : (s == 2) ? OFF_QN : OFF_VC;
        for (int idx = tid; idx < 128 * 16; idx += 256) {
            int row = idx >> 4, slot = idx & 15;
            float inv = nrm ? __fdividef(1.f, sNrm[row] + 1e-6f) : 1.f;
            short8 v = *(const short8*)((const char*)sU + swz256(row, slot * 16));
            float4 o0, o1;
            o0.x = b2f((u16)v[0]) * inv; o0.y = b2f((u16)v[1]) * inv;
            o0.z = b2f((u16)v[2]) * inv; o0.w = b2f((u16)v[3]) * inv;
            o1.x = b2f((u16)v[4]) * inv; o1.y = b2f((u16)v[5]) * inv;
            o1.z = b2f((u16)v[6]) * inv; o1.w = b2f((u16)v[7]) * inv;
            size_t base = off + (size_t)(m0 + row) * 8192 + g * 128 + slot * 8;
            *(float4*)&out[base] = o0;
            *(float4*)&out[base + 4] = o1;
        }
    }
    __syncthreads();

    // nov column -> w_nov (x_out bf16 in sH)
    {
        int row = tid >> 1, half = tid & 1;
        float accn = 0.f;
        #pragma unroll
        for (int i = 0; i < 8; ++i) {
            short8 v = *(const short8*)((const char*)sH + swz256(row, (half * 64 + i * 8) * 2));
            #pragma unroll
            for (int jj = 0; jj < 8; ++jj) accn += b2f((u16)v[jj]) * sNov[half * 64 + i * 8 + jj];
        }
        accn += __shfl_xor(accn, 1);
        if (half == 0) {
            float nv = accn + b_post[g * 513 + 512];
            out[OFF_WN + (size_t)(m0 + row) * 64 + g] = __fdividef(1.f, 1.f + __expf(-nv));
        }
    }
}

extern "C" void kernel_launch(void* const* d_in, const int* in_sizes, int n_in,
                              void* d_out, int out_size, void* d_ws, size_t ws_size,
                              hipStream_t stream) {
    const float* x_col      = (const float*)d_in[0];
    const float* z_hat_prev = (const float*)d_in[1];
    const float* gamma      = (const float*)d_in[2];
    const float* beta       = (const float*)d_in[3];
    const float* W_up       = (const float*)d_in[4];
    const float* b_up       = (const float*)d_in[5];
    const float* W_down     = (const float*)d_in[6];
    const float* b_down     = (const float*)d_in[7];
    const float* W_post     = (const float*)d_in[8];
    const float* b_post     = (const float*)d_in[9];
    const float* W_enc      = (const float*)d_in[10];
    const float* b_enc      = (const float*)d_in[11];
    const float* W_pred     = (const float*)d_in[12];
    const float* b_pred     = (const float*)d_in[13];
    const float* W_gain     = (const float*)d_in[14];
    const float* b_gain     = (const float*)d_in[15];
    float* out = (float*)d_out;
    u16* ws = (u16*)d_ws;

    kconv_all<<<3520, 256, 0, stream>>>(W_up, W_down, W_post, W_enc, W_gain, W_pred, ws);
    kfused<<<1024, 256, 0, stream>>>(x_col, z_hat_prev, gamma, beta,
                                     b_enc, b_pred, b_gain, b_up, b_down, b_post,
                                     ws, out);
}

// Round 5
// 358.530 us; speedup vs baseline: 4.5651x; 1.3566x over previous
//
#include <hip/hip_runtime.h>

typedef unsigned short u16;
typedef __attribute__((ext_vector_type(4))) unsigned short u16x4;
typedef __attribute__((ext_vector_type(8))) short short8;
typedef __attribute__((ext_vector_type(16))) float f32x16;

#define MFMA(a,b,c) __builtin_amdgcn_mfma_f32_32x32x16_bf16((a),(b),(c),0,0,0)

// ---- output offsets (floats), reference return order ----
static constexpr size_t OFF_XOUT = 0;
static constexpr size_t OFF_Z    = 16777216;
static constexpr size_t OFF_ZHAT = 20971520;
static constexpr size_t OFF_SUR  = 25165824;
static constexpr size_t OFF_KC   = 25296896;
static constexpr size_t OFF_VP   = 42074112;
static constexpr size_t OFF_GATE = 58851328;
static constexpr size_t OFF_QN   = 58982400;
static constexpr size_t OFF_VC   = 75759616;
static constexpr size_t OFF_WN   = 92536832;
static constexpr size_t OFF_S5   = 92667904;

// ---- workspace offsets (u16 elements): transposed bf16 weights ----
static constexpr size_t WUP_T = 0;          // [G][512][128]
static constexpr size_t WDN_T = 4194304;    // [G][128][512]
static constexpr size_t WPO_T = 8388608;    // [G][513][128]
static constexpr size_t WEN_T = 12591104;   // [G][32][128]
static constexpr size_t WGN_T = 12853248;   // [G][128][32]
static constexpr size_t WPR_T = 13115392;   // [G][32][32]

__device__ __forceinline__ u16 f2b(float f) {
    unsigned u = __float_as_uint(f);
    unsigned r = (u + 0x7FFFu + ((u >> 16) & 1u)) >> 16;
    return (u16)r;
}
__device__ __forceinline__ float b2f(u16 b) {
    return __uint_as_float(((unsigned)b) << 16);
}
// swizzles for [R][128]bf16 (256B rows) and [R][32]bf16 (64B rows)
__device__ __forceinline__ int swz256(int row, int b) {
    return row * 256 + (b ^ ((row & 7) << 4) ^ (((row >> 3) & 1) << 7));
}
__device__ __forceinline__ int swz64(int row, int b) {
    return row * 64 + (b ^ ((row & 3) << 4));
}
// A/B fragment loads for mfma_f32_32x32x16_bf16: lane holds 8 contiguous k,
// row/col = lane&31, k-half = lane>>5.
__device__ __forceinline__ short8 fragLd256(const u16* s, int row, int ks) {
    int b = ks * 32 + ((threadIdx.x >> 5) & 1) * 16;
    return *(const short8*)((const char*)s + swz256(row, b));
}
__device__ __forceinline__ short8 fragLd64(const u16* s, int row, int ks) {
    int b = ks * 32 + ((threadIdx.x >> 5) & 1) * 16;
    return *(const short8*)((const char*)s + swz64(row, b));
}
__device__ __forceinline__ float tanh_f(float x) {
    float xc = fminf(fmaxf(x, -15.f), 15.f);
    float e = __expf(2.f * xc);
    return __fdividef(e - 1.f, e + 1.f);
}
__device__ __forceinline__ float gelu_f(float u) {
    float y = 0.7978845608f * (u + 0.044715f * u * u * u);
    return 0.5f * u * (1.f + tanh_f(y));
}

// ---------------- fused transpose+convert for all six weights ----------------
// src[G][K][C] f32 -> dst[G][C][K] bf16
__global__ __launch_bounds__(256)
void kconv_all(const float* __restrict__ W_up, const float* __restrict__ W_down,
               const float* __restrict__ W_post, const float* __restrict__ W_enc,
               const float* __restrict__ W_gain, const float* __restrict__ W_pred,
               u16* __restrict__ ws)
{
    int b = blockIdx.x;
    const float* src; u16* dst; int K, C, bx;
    if (b < 1024)      { src = W_up;   dst = ws + WUP_T; K = 128; C = 512; bx = 8; }
    else if (b < 2048) { b -= 1024; src = W_down; dst = ws + WDN_T; K = 512; C = 128; bx = 2; }
    else if (b < 3200) { b -= 2048; src = W_post; dst = ws + WPO_T; K = 128; C = 513; bx = 9; }
    else if (b < 3328) { b -= 3200; src = W_enc;  dst = ws + WEN_T; K = 128; C = 32;  bx = 1; }
    else if (b < 3456) { b -= 3328; src = W_gain; dst = ws + WGN_T; K = 32;  C = 128; bx = 2; }
    else               { b -= 3456; src = W_pred; dst = ws + WPR_T; K = 32;  C = 32;  bx = 1; }
    const int by = (K + 63) >> 6;
    const int nb = bx * by;
    const int g = b / nb, r = b % nb;
    const int c0 = (r % bx) * 64, k0 = (r / bx) * 64;

    __shared__ float sT[64][65];
    const float* s = src + (size_t)g * K * C;
    u16* d = dst + (size_t)g * K * C;
    for (int e = threadIdx.x; e < 64 * 64; e += 256) {
        int kk = e >> 6, cc = e & 63;
        if (k0 + kk < K && c0 + cc < C)
            sT[kk][cc] = s[(size_t)(k0 + kk) * C + c0 + cc];
    }
    __syncthreads();
    for (int e = threadIdx.x; e < 64 * 64; e += 256) {
        int cc = e >> 6, kk = e & 63;
        if (k0 + kk < K && c0 + cc < C)
            d[(size_t)(c0 + cc) * K + k0 + kk] = f2b(sT[kk][cc]);
    }
}

// ---------------- fully fused main kernel (512 threads = 8 waves) ----------------
__global__ __launch_bounds__(512, 2)
void kfused(const float* __restrict__ x_col,
            const float* __restrict__ z_hat_prev,
            const float* __restrict__ gamma,
            const float* __restrict__ beta,
            const float* __restrict__ b_enc,
            const float* __restrict__ b_pred,
            const float* __restrict__ b_gain,
            const float* __restrict__ b_up,
            const float* __restrict__ b_down,
            const float* __restrict__ b_post,
            const u16* __restrict__ ws,
            float* __restrict__ out)
{
    // XCD-aware mapping: blocks with the same XCD residue (bid&7) cover a
    // contiguous set of 8 groups -> weight working set ~3.1MB fits per-XCD L2.
    const int bid = blockIdx.x;
    const int xc = bid & 7, j = bid >> 3;
    const int g = xc * 8 + (j >> 4);
    const int tile = j & 15;
    const int m0 = tile * 128;

    const int tid = threadIdx.x, lane = tid & 63;
    const int w8 = tid >> 6;                 // wave id 0..7
    const int wr = w8 >> 2;                  // row half (64 rows)
    const int wcc = w8 & 3;                  // col frag (32 cols)
    const int l31 = lane & 31, lh = lane >> 5;

    __shared__ u16 sX[128 * 128];   // x bf16 (phase A + residual)
    __shared__ u16 sH[128 * 128];   // h (A->B), then x_out bf16 (B->C)
    __shared__ u16 sW[128 * 128];   // weight staging (all phases)
    __shared__ u16 sU[128 * 128];   // A: D/Z subregions; B: gelu out; C: sP
    __shared__ float sMu[128], sRstd[128], sNrm[128], sNov[128];

    const u16* wPo = ws + WPO_T + (size_t)g * 65664;

    // ---- phase A staging ----
    // Small weights packed INSIDE sW (u16-element offsets):
    //   sWe bytes [0,8192): Wenc^T [32][128] swz256
    //   sWg bytes [16384,24576): Wgain^T [128][32] swz64
    //   sWp bytes [24576,26624): Wpred^T [32][32] swz64
    u16* sWe = sW;
    u16* sWg = sW + 8192;
    u16* sWp = sW + 12288;
    u16* sD  = sU;               // delta [128][32] swz64, bytes [0,8192)
    u16* sZ  = sU + 4096;        // z     [128][32] swz64, bytes [8192,16384)

    for (int idx = tid; idx < 128 * 32; idx += 512) {
        int row = idx >> 5, q = idx & 31;
        float4 v = *(const float4*)&x_col[(size_t)(m0 + row) * 8192 + g * 128 + q * 4];
        u16x4 bv; bv.x = f2b(v.x); bv.y = f2b(v.y); bv.z = f2b(v.z); bv.w = f2b(v.w);
        *(u16x4*)((char*)sX + swz256(row, q * 8)) = bv;
    }
    for (int idx = tid; idx < 32 * 16; idx += 512) {
        int row = idx >> 4, slot = idx & 15;
        short8 v = *(const short8*)(ws + WEN_T + ((size_t)g * 32 + row) * 128 + slot * 8);
        *(short8*)((char*)sWe + swz256(row, slot * 16)) = v;
    }
    for (int idx = tid; idx < 128 * 4; idx += 512) {
        int row = idx >> 2, slot = idx & 3;
        short8 v = *(const short8*)(ws + WGN_T + ((size_t)g * 128 + row) * 32 + slot * 8);
        *(short8*)((char*)sWg + swz64(row, slot * 16)) = v;
    }
    if (tid < 128) {
        int row = tid >> 2, slot = tid & 3;
        short8 v = *(const short8*)(ws + WPR_T + ((size_t)g * 32 + row) * 32 + slot * 8);
        *(short8*)((char*)sWp + swz64(row, slot * 16)) = v;
        sNov[tid] = b2f(wPo[(size_t)512 * 128 + tid]);
    }
    __syncthreads();

    // ---- phase A step 1: {waves 0-3: enc GEMM} || {waves 4-7: LN stats} ----
    if (w8 < 4) {
        f32x16 zacc = (f32x16)0.f;
        #pragma unroll
        for (int ks = 0; ks < 8; ++ks) {
            short8 a = fragLd256(sX, 32 * w8 + l31, ks);
            short8 b = fragLd256(sWe, l31, ks);
            zacc = MFMA(a, b, zacc);
        }
        float benc = b_enc[g * 32 + l31];
        #pragma unroll
        for (int r = 0; r < 16; ++r) {
            float zv = zacc[r] + benc;
            int row = 32 * w8 + (r & 3) + 8 * (r >> 2) + 4 * lh;
            size_t zoff = (size_t)(m0 + row) * 2048 + g * 32 + l31;
            out[OFF_Z + zoff] = zv;
            float d = zv - z_hat_prev[zoff];
            *(u16*)((char*)sD + swz64(row, l31 * 2)) = f2b(d);
            *(u16*)((char*)sZ + swz64(row, l31 * 2)) = f2b(zv);
            float ss = d * d;
            ss += __shfl_xor(ss, 1); ss += __shfl_xor(ss, 2); ss += __shfl_xor(ss, 4);
            ss += __shfl_xor(ss, 8); ss += __shfl_xor(ss, 16);
            if (l31 == 0) {
                float sur = sqrtf(ss);
                size_t p = (size_t)(m0 + row) * 64 + g;
                out[OFF_SUR + p] = sur;
                out[OFF_S5 + p] = sur;
                out[OFF_GATE + p] = fminf(fmaxf(sur, 0.f), 1.f);
            }
        }
    } else {
        int t = tid & 255;
        int row = t >> 1, half = t & 1;
        float s1 = 0.f, s2 = 0.f;
        #pragma unroll
        for (int i = 0; i < 8; ++i) {
            short8 v = *(const short8*)((const char*)sX + swz256(row, (half * 64 + i * 8) * 2));
            #pragma unroll
            for (int jj = 0; jj < 8; ++jj) { float x = b2f((u16)v[jj]); s1 += x; s2 += x * x; }
        }
        s1 += __shfl_xor(s1, 1); s2 += __shfl_xor(s2, 1);
        if (half == 0) {
            float mu = s1 * (1.f / 128.f);
            float var = s2 * (1.f / 128.f) - mu * mu;
            sMu[row] = mu; sRstd[row] = rsqrtf(var + 1e-5f);
        }
    }
    __syncthreads();

    // ---- phase A step 2: {waves 4-7: pred GEMM} || {waves 0-3: gain + LN apply} ----
    if (w8 >= 4) {
        int wp = w8 - 4;
        f32x16 pacc = (f32x16)0.f;
        #pragma unroll
        for (int ks = 0; ks < 2; ++ks) {
            short8 a = fragLd64(sZ, 32 * wp + l31, ks);
            short8 b = fragLd64(sWp, l31, ks);
            pacc = MFMA(a, b, pacc);
        }
        float bpred = b_pred[g * 32 + l31];
        #pragma unroll
        for (int r = 0; r < 16; ++r) {
            int row = 32 * wp + (r & 3) + 8 * (r >> 2) + 4 * lh;
            out[OFF_ZHAT + (size_t)(m0 + row) * 2048 + g * 32 + l31] = pacc[r] + bpred;
        }
    } else {
        f32x16 gacc[4];
        #pragma unroll
        for (int c = 0; c < 4; ++c) gacc[c] = (f32x16)0.f;
        #pragma unroll
        for (int ks = 0; ks < 2; ++ks) {
            short8 a = fragLd64(sD, 32 * w8 + l31, ks);
            #pragma unroll
            for (int c = 0; c < 4; ++c) {
                short8 b = fragLd64(sWg, 32 * c + l31, ks);
                gacc[c] = MFMA(a, b, gacc[c]);
            }
        }
        #pragma unroll
        for (int c = 0; c < 4; ++c) {
            int col = 32 * c + l31;
            float bg = b_gain[g * 128 + col];
            float gam = gamma[g * 128 + col];
            float bet = beta[g * 128 + col];
            #pragma unroll
            for (int r = 0; r < 16; ++r) {
                int row = 32 * w8 + (r & 3) + 8 * (r >> 2) + 4 * lh;
                float gain = 1.f + 0.1f * tanh_f(gacc[c][r] + bg);
                float xv = b2f(*(const u16*)((const char*)sX + swz256(row, col * 2)));
                float h = ((xv - sMu[row]) * sRstd[row] * gam + bet) * gain;
                *(u16*)((char*)sH + swz256(row, col * 2)) = f2b(h);
            }
        }
    }
    // sH writes are protected by the sync at the top of the first B-chunk.

    // ---- phase B: MLP. Wave grid: wr in {0,1} x wcc in {0..3} ----
    const u16* wUp = ws + WUP_T + (size_t)g * 65536;
    const u16* wDn = ws + WDN_T + (size_t)g * 65536;

    f32x16 dacc[2];
    dacc[0] = (f32x16)0.f; dacc[1] = (f32x16)0.f;

    for (int ch = 0; ch < 4; ++ch) {
        const int c0 = ch * 128;
        __syncthreads();   // protects sW (prev readers done) and sH (A writers done)
        for (int idx = tid; idx < 128 * 16; idx += 512) {   // W_upT chunk [c][k]
            int row = idx >> 4, slot = idx & 15;
            short8 v = *(const short8*)(wUp + (size_t)(c0 + row) * 128 + slot * 8);
            *(short8*)((char*)sW + swz256(row, slot * 16)) = v;
        }
        __syncthreads();

        f32x16 uacc[2];
        uacc[0] = (f32x16)0.f; uacc[1] = (f32x16)0.f;
        #pragma unroll
        for (int ks = 0; ks < 8; ++ks) {
            short8 a0 = fragLd256(sH, 64 * wr + l31, ks);
            short8 a1 = fragLd256(sH, 64 * wr + 32 + l31, ks);
            short8 b  = fragLd256(sW, 32 * wcc + l31, ks);
            uacc[0] = MFMA(a0, b, uacc[0]);
            uacc[1] = MFMA(a1, b, uacc[1]);
        }
        {
            float bup = b_up[(size_t)g * 512 + c0 + 32 * wcc + l31];
            int colB = (32 * wcc + l31) * 2;
            #pragma unroll
            for (int f = 0; f < 2; ++f)
                #pragma unroll
                for (int r = 0; r < 16; ++r) {
                    int row = 64 * wr + 32 * f + (r & 3) + 8 * (r >> 2) + 4 * lh;
                    float gel = gelu_f(uacc[f][r] + bup);
                    *(u16*)((char*)sU + swz256(row, colB)) = f2b(gel);
                }
        }
        __syncthreads();   // sU (gelu) complete; sW (up) readers done
        for (int idx = tid; idx < 128 * 16; idx += 512) {   // W_downT chunk [j][c-slice]
            int row = idx >> 4, slot = idx & 15;
            short8 v = *(const short8*)(wDn + (size_t)row * 512 + c0 + slot * 8);
            *(short8*)((char*)sW + swz256(row, slot * 16)) = v;
        }
        __syncthreads();
        #pragma unroll
        for (int ks = 0; ks < 8; ++ks) {
            short8 a0 = fragLd256(sU, 64 * wr + l31, ks);
            short8 a1 = fragLd256(sU, 64 * wr + 32 + l31, ks);
            short8 b  = fragLd256(sW, 32 * wcc + l31, ks);
            dacc[0] = MFMA(a0, b, dacc[0]);
            dacc[1] = MFMA(a1, b, dacc[1]);
        }
    }

    // epilogue: x_out = x + b_down + mlp -> global f32 + sH bf16.
    // (All sH readers of phase B passed the last staging barrier already.)
    {
        int jc = 32 * wcc + l31;
        float bd = b_down[g * 128 + jc];
        #pragma unroll
        for (int f = 0; f < 2; ++f)
            #pragma unroll
            for (int r = 0; r < 16; ++r) {
                int row = 64 * wr + 32 * f + (r & 3) + 8 * (r >> 2) + 4 * lh;
                size_t base = (size_t)(m0 + row) * 8192 + g * 128 + jc;
                float xo = b2f(*(const u16*)((const char*)sX + swz256(row, jc * 2)))
                           + bd + dacc[f][r];
                out[OFF_XOUT + base] = xo;
                *(u16*)((char*)sH + swz256(row, jc * 2)) = f2b(xo);
            }
    }

    // ---- phase C: post-proj (sH = x_out bf16, sU = sP) ----
    for (int s = 0; s < 4; ++s) {
        __syncthreads();   // sH epilogue writes + prev-slice sU readers done
        for (int idx = tid; idx < 128 * 16; idx += 512) {   // W_postT slice [c][k]
            int row = idx >> 4, slot = idx & 15;
            short8 v = *(const short8*)(wPo + (size_t)(s * 128 + row) * 128 + slot * 8);
            *(short8*)((char*)sW + swz256(row, slot * 16)) = v;
        }
        __syncthreads();

        f32x16 acc[2];
        acc[0] = (f32x16)0.f; acc[1] = (f32x16)0.f;
        #pragma unroll
        for (int ks = 0; ks < 8; ++ks) {
            short8 a0 = fragLd256(sH, 64 * wr + l31, ks);
            short8 a1 = fragLd256(sH, 64 * wr + 32 + l31, ks);
            short8 b  = fragLd256(sW, 32 * wcc + l31, ks);
            acc[0] = MFMA(a0, b, acc[0]);
            acc[1] = MFMA(a1, b, acc[1]);
        }
        {
            float bp = b_post[g * 513 + s * 128 + 32 * wcc + l31];
            int colB = (32 * wcc + l31) * 2;
            #pragma unroll
            for (int f = 0; f < 2; ++f)
                #pragma unroll
                for (int r = 0; r < 16; ++r) {
                    int row = 64 * wr + 32 * f + (r & 3) + 8 * (r >> 2) + 4 * lh;
                    *(u16*)((char*)sU + swz256(row, colB)) = f2b(acc[f][r] + bp);
                }
        }
        __syncthreads();

        const bool nrm = (s == 0 || s == 2);
        if (nrm) {
            int row = tid >> 2, part = tid & 3;
            float ss = 0.f;
            #pragma unroll
            for (int i = 0; i < 4; ++i) {
                short8 v = *(const short8*)((const char*)sU + swz256(row, (part * 32 + i * 8) * 2));
                #pragma unroll
                for (int jj = 0; jj < 8; ++jj) { float x = b2f((u16)v[jj]); ss += x * x; }
            }
            ss += __shfl_xor(ss, 1); ss += __shfl_xor(ss, 2);
            if (part == 0) sNrm[row] = sqrtf(ss);
            __syncthreads();
        }
        size_t off = (s == 0) ? OFF_KC : (s == 1) ? OFF_VP : (s == 2) ? OFF_QN : OFF_VC;
        for (int idx = tid; idx < 128 * 16; idx += 512) {
            int row = idx >> 4, slot = idx & 15;
            float inv = nrm ? __fdividef(1.f, sNrm[row] + 1e-6f) : 1.f;
            short8 v = *(const short8*)((const char*)sU + swz256(row, slot * 16));
            float4 o0, o1;
            o0.x = b2f((u16)v[0]) * inv; o0.y = b2f((u16)v[1]) * inv;
            o0.z = b2f((u16)v[2]) * inv; o0.w = b2f((u16)v[3]) * inv;
            o1.x = b2f((u16)v[4]) * inv; o1.y = b2f((u16)v[5]) * inv;
            o1.z = b2f((u16)v[6]) * inv; o1.w = b2f((u16)v[7]) * inv;
            size_t base = off + (size_t)(m0 + row) * 8192 + g * 128 + slot * 8;
            *(float4*)&out[base] = o0;
            *(float4*)&out[base + 4] = o1;
        }
    }
    __syncthreads();

    // nov column -> w_nov (x_out bf16 in sH)
    {
        int row = tid >> 2, part = tid & 3;
        float accn = 0.f;
        #pragma unroll
        for (int i = 0; i < 4; ++i) {
            short8 v = *(const short8*)((const char*)sH + swz256(row, (part * 32 + i * 8) * 2));
            #pragma unroll
            for (int jj = 0; jj < 8; ++jj) accn += b2f((u16)v[jj]) * sNov[part * 32 + i * 8 + jj];
        }
        accn += __shfl_xor(accn, 1); accn += __shfl_xor(accn, 2);
        if (part == 0) {
            float nv = accn + b_post[g * 513 + 512];
            out[OFF_WN + (size_t)(m0 + row) * 64 + g] = __fdividef(1.f, 1.f + __expf(-nv));
        }
    }
}

extern "C" void kernel_launch(void* const* d_in, const int* in_sizes, int n_in,
                              void* d_out, int out_size, void* d_ws, size_t ws_size,
                              hipStream_t stream) {
    const float* x_col      = (const float*)d_in[0];
    const float* z_hat_prev = (const float*)d_in[1];
    const float* gamma      = (const float*)d_in[2];
    const float* beta       = (const float*)d_in[3];
    const float* W_up       = (const float*)d_in[4];
    const float* b_up       = (const float*)d_in[5];
    const float* W_down     = (const float*)d_in[6];
    const float* b_down     = (const float*)d_in[7];
    const float* W_post     = (const float*)d_in[8];
    const float* b_post     = (const float*)d_in[9];
    const float* W_enc      = (const float*)d_in[10];
    const float* b_enc      = (const float*)d_in[11];
    const float* W_pred     = (const float*)d_in[12];
    const float* b_pred     = (const float*)d_in[13];
    const float* W_gain     = (const float*)d_in[14];
    const float* b_gain     = (const float*)d_in[15];
    float* out = (float*)d_out;
    u16* ws = (u16*)d_ws;

    kconv_all<<<3520, 256, 0, stream>>>(W_up, W_down, W_post, W_enc, W_gain, W_pred, ws);
    kfused<<<1024, 512, 0, stream>>>(x_col, z_hat_prev, gamma, beta,
                                     b_enc, b_pred, b_gain, b_up, b_down, b_post,
                                     ws, out);
}

// Round 6
// 334.080 us; speedup vs baseline: 4.8992x; 1.0732x over previous
//
#include <hip/hip_runtime.h>

typedef unsigned short u16;
typedef __attribute__((ext_vector_type(4))) unsigned short u16x4;
typedef __attribute__((ext_vector_type(8))) short short8;
typedef __attribute__((ext_vector_type(16))) float f32x16;

#define MFMA(a,b,c) __builtin_amdgcn_mfma_f32_32x32x16_bf16((a),(b),(c),0,0,0)

// ---- output offsets (floats), reference return order ----
static constexpr size_t OFF_XOUT = 0;
static constexpr size_t OFF_Z    = 16777216;
static constexpr size_t OFF_ZHAT = 20971520;
static constexpr size_t OFF_SUR  = 25165824;
static constexpr size_t OFF_KC   = 25296896;
static constexpr size_t OFF_VP   = 42074112;
static constexpr size_t OFF_GATE = 58851328;
static constexpr size_t OFF_QN   = 58982400;
static constexpr size_t OFF_VC   = 75759616;
static constexpr size_t OFF_WN   = 92536832;
static constexpr size_t OFF_S5   = 92667904;

// ---- workspace offsets (u16 elements): transposed bf16 weights ----
static constexpr size_t WUP_T = 0;          // [G][512][128]
static constexpr size_t WDN_T = 4194304;    // [G][128][512]
static constexpr size_t WPO_T = 8388608;    // [G][513][128]
static constexpr size_t WEN_T = 12591104;   // [G][32][128]
static constexpr size_t WGN_T = 12853248;   // [G][128][32]
static constexpr size_t WPR_T = 13115392;   // [G][32][32]

__device__ __forceinline__ u16 f2b(float f) {
    unsigned u = __float_as_uint(f);
    unsigned r = (u + 0x7FFFu + ((u >> 16) & 1u)) >> 16;
    return (u16)r;
}
__device__ __forceinline__ float b2f(u16 b) {
    return __uint_as_float(((unsigned)b) << 16);
}
// swizzles for [R][128]bf16 (256B rows) and [R][32]bf16 (64B rows)
__device__ __forceinline__ int swz256(int row, int b) {
    return row * 256 + (b ^ ((row & 7) << 4) ^ (((row >> 3) & 1) << 7));
}
__device__ __forceinline__ int swz64(int row, int b) {
    return row * 64 + (b ^ ((row & 3) << 4));
}
// A/B fragment loads for mfma_f32_32x32x16_bf16: lane holds 8 contiguous k,
// row/col = lane&31, k-half = lane>>5.
__device__ __forceinline__ short8 fragLd256(const u16* s, int row, int ks) {
    int b = ks * 32 + ((threadIdx.x >> 5) & 1) * 16;
    return *(const short8*)((const char*)s + swz256(row, b));
}
__device__ __forceinline__ short8 fragLd64(const u16* s, int row, int ks) {
    int b = ks * 32 + ((threadIdx.x >> 5) & 1) * 16;
    return *(const short8*)((const char*)s + swz64(row, b));
}
__device__ __forceinline__ float tanh_f(float x) {
    float xc = fminf(fmaxf(x, -15.f), 15.f);
    float e = __expf(2.f * xc);
    return __fdividef(e - 1.f, e + 1.f);
}
__device__ __forceinline__ float gelu_f(float u) {
    float y = 0.7978845608f * (u + 0.044715f * u * u * u);
    return 0.5f * u * (1.f + tanh_f(y));
}

// ---------------- fused transpose+convert for all six weights ----------------
// src[G][K][C] f32 -> dst[G][C][K] bf16
__global__ __launch_bounds__(256)
void kconv_all(const float* __restrict__ W_up, const float* __restrict__ W_down,
               const float* __restrict__ W_post, const float* __restrict__ W_enc,
               const float* __restrict__ W_gain, const float* __restrict__ W_pred,
               u16* __restrict__ ws)
{
    int b = blockIdx.x;
    const float* src; u16* dst; int K, C, bx;
    if (b < 1024)      { src = W_up;   dst = ws + WUP_T; K = 128; C = 512; bx = 8; }
    else if (b < 2048) { b -= 1024; src = W_down; dst = ws + WDN_T; K = 512; C = 128; bx = 2; }
    else if (b < 3200) { b -= 2048; src = W_post; dst = ws + WPO_T; K = 128; C = 513; bx = 9; }
    else if (b < 3328) { b -= 3200; src = W_enc;  dst = ws + WEN_T; K = 128; C = 32;  bx = 1; }
    else if (b < 3456) { b -= 3328; src = W_gain; dst = ws + WGN_T; K = 32;  C = 128; bx = 2; }
    else               { b -= 3456; src = W_pred; dst = ws + WPR_T; K = 32;  C = 32;  bx = 1; }
    const int by = (K + 63) >> 6;
    const int nb = bx * by;
    const int g = b / nb, r = b % nb;
    const int c0 = (r % bx) * 64, k0 = (r / bx) * 64;

    __shared__ float sT[64][65];
    const float* s = src + (size_t)g * K * C;
    u16* d = dst + (size_t)g * K * C;
    for (int e = threadIdx.x; e < 64 * 64; e += 256) {
        int kk = e >> 6, cc = e & 63;
        if (k0 + kk < K && c0 + cc < C)
            sT[kk][cc] = s[(size_t)(k0 + kk) * C + c0 + cc];
    }
    __syncthreads();
    for (int e = threadIdx.x; e < 64 * 64; e += 256) {
        int cc = e >> 6, kk = e & 63;
        if (k0 + kk < K && c0 + cc < C)
            d[(size_t)(c0 + cc) * K + k0 + kk] = f2b(sT[kk][cc]);
    }
}

// ---------------- fully fused main kernel (1024 threads = 16 waves) ----------------
__global__ __launch_bounds__(1024, 4)
void kfused(const float* __restrict__ x_col,
            const float* __restrict__ z_hat_prev,
            const float* __restrict__ gamma,
            const float* __restrict__ beta,
            const float* __restrict__ b_enc,
            const float* __restrict__ b_pred,
            const float* __restrict__ b_gain,
            const float* __restrict__ b_up,
            const float* __restrict__ b_down,
            const float* __restrict__ b_post,
            const u16* __restrict__ ws,
            float* __restrict__ out)
{
    // XCD-aware mapping: blocks with the same XCD residue (bid&7) cover a
    // contiguous set of 8 groups -> weight working set ~3.1MB fits per-XCD L2.
    const int bid = blockIdx.x;
    const int xc = bid & 7, j = bid >> 3;
    const int g = xc * 8 + (j >> 4);
    const int tile = j & 15;
    const int m0 = tile * 128;

    const int tid = threadIdx.x, lane = tid & 63;
    const int w16 = tid >> 6;                // wave id 0..15
    const int wr = w16 >> 2;                 // row frag (32 rows)
    const int wc = w16 & 3;                  // col frag (32 cols)
    const int l31 = lane & 31, lh = lane >> 5;

    __shared__ u16 sX[128 * 128];   // x bf16 (phase A + residual)
    __shared__ u16 sH[128 * 128];   // h (A->B), then x_out bf16 (B->C)
    __shared__ u16 sW[128 * 128];   // weight staging (all phases)
    __shared__ u16 sU[128 * 128];   // A: D/Z subregions; B: gelu out; C: sP
    __shared__ float sMu[128], sRstd[128], sNrm[128], sNov[128];

    const u16* wPo = ws + WPO_T + (size_t)g * 65664;

    // ---- phase A staging ----
    // Small weights packed INSIDE sW (u16-element offsets):
    //   sWe bytes [0,16384): Wenc^T [32][128] swz256
    //   sWg bytes [16384,24576): Wgain^T [128][32] swz64
    //   sWp bytes [24576,26624): Wpred^T [32][32] swz64
    u16* sWe = sW;
    u16* sWg = sW + 8192;
    u16* sWp = sW + 12288;
    u16* sD  = sU;               // delta [128][32] swz64, bytes [0,8192)
    u16* sZ  = sU + 4096;        // z     [128][32] swz64, bytes [8192,16384)

    for (int idx = tid; idx < 128 * 32; idx += 1024) {
        int row = idx >> 5, q = idx & 31;
        float4 v = *(const float4*)&x_col[(size_t)(m0 + row) * 8192 + g * 128 + q * 4];
        u16x4 bv; bv.x = f2b(v.x); bv.y = f2b(v.y); bv.z = f2b(v.z); bv.w = f2b(v.w);
        *(u16x4*)((char*)sX + swz256(row, q * 8)) = bv;
    }
    if (tid < 32 * 16) {
        int row = tid >> 4, slot = tid & 15;
        short8 v = *(const short8*)(ws + WEN_T + ((size_t)g * 32 + row) * 128 + slot * 8);
        *(short8*)((char*)sWe + swz256(row, slot * 16)) = v;
    }
    if (tid < 128 * 4) {
        int row = tid >> 2, slot = tid & 3;
        short8 v = *(const short8*)(ws + WGN_T + ((size_t)g * 128 + row) * 32 + slot * 8);
        *(short8*)((char*)sWg + swz64(row, slot * 16)) = v;
    }
    if (tid < 128) {
        int row = tid >> 2, slot = tid & 3;
        short8 v = *(const short8*)(ws + WPR_T + ((size_t)g * 32 + row) * 32 + slot * 8);
        *(short8*)((char*)sWp + swz64(row, slot * 16)) = v;
        sNov[tid] = b2f(wPo[(size_t)512 * 128 + tid]);
    }
    __syncthreads();

    // ---- phase A step 1: {waves 0-3: enc GEMM} || {waves 4-7: LN stats} ----
    if (w16 < 4) {
        f32x16 zacc = (f32x16)0.f;
        #pragma unroll
        for (int ks = 0; ks < 8; ++ks) {
            short8 a = fragLd256(sX, 32 * w16 + l31, ks);
            short8 b = fragLd256(sWe, l31, ks);
            zacc = MFMA(a, b, zacc);
        }
        float benc = b_enc[g * 32 + l31];
        #pragma unroll
        for (int r = 0; r < 16; ++r) {
            float zv = zacc[r] + benc;
            int row = 32 * w16 + (r & 3) + 8 * (r >> 2) + 4 * lh;
            size_t zoff = (size_t)(m0 + row) * 2048 + g * 32 + l31;
            out[OFF_Z + zoff] = zv;
            float d = zv - z_hat_prev[zoff];
            *(u16*)((char*)sD + swz64(row, l31 * 2)) = f2b(d);
            *(u16*)((char*)sZ + swz64(row, l31 * 2)) = f2b(zv);
            float ss = d * d;
            ss += __shfl_xor(ss, 1); ss += __shfl_xor(ss, 2); ss += __shfl_xor(ss, 4);
            ss += __shfl_xor(ss, 8); ss += __shfl_xor(ss, 16);
            if (l31 == 0) {
                float sur = sqrtf(ss);
                size_t p = (size_t)(m0 + row) * 64 + g;
                out[OFF_SUR + p] = sur;
                out[OFF_S5 + p] = sur;
                out[OFF_GATE + p] = fminf(fmaxf(sur, 0.f), 1.f);
            }
        }
    } else if (w16 < 8) {
        int t = tid - 256;
        int row = t >> 1, half = t & 1;
        float s1 = 0.f, s2 = 0.f;
        #pragma unroll
        for (int i = 0; i < 8; ++i) {
            short8 v = *(const short8*)((const char*)sX + swz256(row, (half * 64 + i * 8) * 2));
            #pragma unroll
            for (int jj = 0; jj < 8; ++jj) { float x = b2f((u16)v[jj]); s1 += x; s2 += x * x; }
        }
        s1 += __shfl_xor(s1, 1); s2 += __shfl_xor(s2, 1);
        if (half == 0) {
            float mu = s1 * (1.f / 128.f);
            float var = s2 * (1.f / 128.f) - mu * mu;
            sMu[row] = mu; sRstd[row] = rsqrtf(var + 1e-5f);
        }
    }
    __syncthreads();

    // ---- phase A step 2: {waves 0-7: gain GEMM + LN apply} || {waves 8-11: pred} ----
    if (w16 < 8) {
        const int wrg = w16 >> 1;      // row frag
        const int cp  = w16 & 1;       // col pair: frags {2cp, 2cp+1}
        f32x16 gacc[2];
        gacc[0] = (f32x16)0.f; gacc[1] = (f32x16)0.f;
        #pragma unroll
        for (int ks = 0; ks < 2; ++ks) {
            short8 a = fragLd64(sD, 32 * wrg + l31, ks);
            #pragma unroll
            for (int k = 0; k < 2; ++k) {
                short8 b = fragLd64(sWg, 32 * (2 * cp + k) + l31, ks);
                gacc[k] = MFMA(a, b, gacc[k]);
            }
        }
        #pragma unroll
        for (int k = 0; k < 2; ++k) {
            int col = 32 * (2 * cp + k) + l31;
            float bg = b_gain[g * 128 + col];
            float gam = gamma[g * 128 + col];
            float bet = beta[g * 128 + col];
            #pragma unroll
            for (int r = 0; r < 16; ++r) {
                int row = 32 * wrg + (r & 3) + 8 * (r >> 2) + 4 * lh;
                float gain = 1.f + 0.1f * tanh_f(gacc[k][r] + bg);
                float xv = b2f(*(const u16*)((const char*)sX + swz256(row, col * 2)));
                float h = ((xv - sMu[row]) * sRstd[row] * gam + bet) * gain;
                *(u16*)((char*)sH + swz256(row, col * 2)) = f2b(h);
            }
        }
    } else if (w16 < 12) {
        int wp = w16 - 8;
        f32x16 pacc = (f32x16)0.f;
        #pragma unroll
        for (int ks = 0; ks < 2; ++ks) {
            short8 a = fragLd64(sZ, 32 * wp + l31, ks);
            short8 b = fragLd64(sWp, l31, ks);
            pacc = MFMA(a, b, pacc);
        }
        float bpred = b_pred[g * 32 + l31];
        #pragma unroll
        for (int r = 0; r < 16; ++r) {
            int row = 32 * wp + (r & 3) + 8 * (r >> 2) + 4 * lh;
            out[OFF_ZHAT + (size_t)(m0 + row) * 2048 + g * 32 + l31] = pacc[r] + bpred;
        }
    }
    // sH writes are protected by the sync at the top of the first B-chunk.

    // ---- phase B: MLP. Wave grid: wr in {0..3} x wc in {0..3} ----
    const u16* wUp = ws + WUP_T + (size_t)g * 65536;
    const u16* wDn = ws + WDN_T + (size_t)g * 65536;

    f32x16 dacc = (f32x16)0.f;

    for (int ch = 0; ch < 4; ++ch) {
        const int c0 = ch * 128;
        __syncthreads();   // protects sW (prev readers done) and sH (A writers done)
        for (int idx = tid; idx < 128 * 16; idx += 1024) {   // W_upT chunk [c][k]
            int row = idx >> 4, slot = idx & 15;
            short8 v = *(const short8*)(wUp + (size_t)(c0 + row) * 128 + slot * 8);
            *(short8*)((char*)sW + swz256(row, slot * 16)) = v;
        }
        __syncthreads();

        f32x16 uacc = (f32x16)0.f;
        #pragma unroll
        for (int ks = 0; ks < 8; ++ks) {
            short8 a = fragLd256(sH, 32 * wr + l31, ks);
            short8 b = fragLd256(sW, 32 * wc + l31, ks);
            uacc = MFMA(a, b, uacc);
        }
        {
            float bup = b_up[(size_t)g * 512 + c0 + 32 * wc + l31];
            int colB = (32 * wc + l31) * 2;
            #pragma unroll
            for (int r = 0; r < 16; ++r) {
                int row = 32 * wr + (r & 3) + 8 * (r >> 2) + 4 * lh;
                float gel = gelu_f(uacc[r] + bup);
                *(u16*)((char*)sU + swz256(row, colB)) = f2b(gel);
            }
        }
        __syncthreads();   // sU (gelu) complete; sW (up) readers done
        for (int idx = tid; idx < 128 * 16; idx += 1024) {   // W_downT chunk [j][c-slice]
            int row = idx >> 4, slot = idx & 15;
            short8 v = *(const short8*)(wDn + (size_t)row * 512 + c0 + slot * 8);
            *(short8*)((char*)sW + swz256(row, slot * 16)) = v;
        }
        __syncthreads();
        #pragma unroll
        for (int ks = 0; ks < 8; ++ks) {
            short8 a = fragLd256(sU, 32 * wr + l31, ks);
            short8 b = fragLd256(sW, 32 * wc + l31, ks);
            dacc = MFMA(a, b, dacc);
        }
    }

    // epilogue: x_out = x + b_down + mlp -> global f32 + sH bf16.
    {
        int jc = 32 * wc + l31;
        float bd = b_down[g * 128 + jc];
        #pragma unroll
        for (int r = 0; r < 16; ++r) {
            int row = 32 * wr + (r & 3) + 8 * (r >> 2) + 4 * lh;
            size_t base = (size_t)(m0 + row) * 8192 + g * 128 + jc;
            float xo = b2f(*(const u16*)((const char*)sX + swz256(row, jc * 2)))
                       + bd + dacc[r];
            out[OFF_XOUT + base] = xo;
            *(u16*)((char*)sH + swz256(row, jc * 2)) = f2b(xo);
        }
    }

    // ---- phase C: post-proj (sH = x_out bf16, sU = sP) ----
    for (int s = 0; s < 4; ++s) {
        __syncthreads();   // sH epilogue writes + prev-slice sU readers done
        for (int idx = tid; idx < 128 * 16; idx += 1024) {   // W_postT slice [c][k]
            int row = idx >> 4, slot = idx & 15;
            short8 v = *(const short8*)(wPo + (size_t)(s * 128 + row) * 128 + slot * 8);
            *(short8*)((char*)sW + swz256(row, slot * 16)) = v;
        }
        __syncthreads();

        f32x16 acc = (f32x16)0.f;
        #pragma unroll
        for (int ks = 0; ks < 8; ++ks) {
            short8 a = fragLd256(sH, 32 * wr + l31, ks);
            short8 b = fragLd256(sW, 32 * wc + l31, ks);
            acc = MFMA(a, b, acc);
        }
        {
            float bp = b_post[g * 513 + s * 128 + 32 * wc + l31];
            int colB = (32 * wc + l31) * 2;
            #pragma unroll
            for (int r = 0; r < 16; ++r) {
                int row = 32 * wr + (r & 3) + 8 * (r >> 2) + 4 * lh;
                *(u16*)((char*)sU + swz256(row, colB)) = f2b(acc[r] + bp);
            }
        }
        __syncthreads();

        const bool nrm = (s == 0 || s == 2);
        if (nrm) {
            int row = tid >> 3, part = tid & 7;
            float ss = 0.f;
            #pragma unroll
            for (int i = 0; i < 2; ++i) {
                short8 v = *(const short8*)((const char*)sU + swz256(row, (part * 16 + i * 8) * 2));
                #pragma unroll
                for (int jj = 0; jj < 8; ++jj) { float x = b2f((u16)v[jj]); ss += x * x; }
            }
            ss += __shfl_xor(ss, 1); ss += __shfl_xor(ss, 2); ss += __shfl_xor(ss, 4);
            if (part == 0) sNrm[row] = sqrtf(ss);
            __syncthreads();
        }
        size_t off = (s == 0) ? OFF_KC : (s == 1) ? OFF_VP : (s == 2) ? OFF_QN : OFF_VC;
        for (int idx = tid; idx < 128 * 16; idx += 1024) {
            int row = idx >> 4, slot = idx & 15;
            float inv = nrm ? __fdividef(1.f, sNrm[row] + 1e-6f) : 1.f;
            short8 v = *(const short8*)((const char*)sU + swz256(row, slot * 16));
            float4 o0, o1;
            o0.x = b2f((u16)v[0]) * inv; o0.y = b2f((u16)v[1]) * inv;
            o0.z = b2f((u16)v[2]) * inv; o0.w = b2f((u16)v[3]) * inv;
            o1.x = b2f((u16)v[4]) * inv; o1.y = b2f((u16)v[5]) * inv;
            o1.z = b2f((u16)v[6]) * inv; o1.w = b2f((u16)v[7]) * inv;
            size_t base = off + (size_t)(m0 + row) * 8192 + g * 128 + slot * 8;
            *(float4*)&out[base] = o0;
            *(float4*)&out[base + 4] = o1;
        }
    }
    __syncthreads();

    // nov column -> w_nov (x_out bf16 in sH)
    {
        int row = tid >> 3, part = tid & 7;
        float accn = 0.f;
        #pragma unroll
        for (int i = 0; i < 2; ++i) {
            short8 v = *(const short8*)((const char*)sH + swz256(row, (part * 16 + i * 8) * 2));
            #pragma unroll
            for (int jj = 0; jj < 8; ++jj) accn += b2f((u16)v[jj]) * sNov[part * 16 + i * 8 + jj];
        }
        accn += __shfl_xor(accn, 1); accn += __shfl_xor(accn, 2); accn += __shfl_xor(accn, 4);
        if (part == 0) {
            float nv = accn + b_post[g * 513 + 512];
            out[OFF_WN + (size_t)(m0 + row) * 64 + g] = __fdividef(1.f, 1.f + __expf(-nv));
        }
    }
}

extern "C" void kernel_launch(void* const* d_in, const int* in_sizes, int n_in,
                              void* d_out, int out_size, void* d_ws, size_t ws_size,
                              hipStream_t stream) {
    const float* x_col      = (const float*)d_in[0];
    const float* z_hat_prev = (const float*)d_in[1];
    const float* gamma      = (const float*)d_in[2];
    const float* beta       = (const float*)d_in[3];
    const float* W_up       = (const float*)d_in[4];
    const float* b_up       = (const float*)d_in[5];
    const float* W_down     = (const float*)d_in[6];
    const float* b_down     = (const float*)d_in[7];
    const float* W_post     = (const float*)d_in[8];
    const float* b_post     = (const float*)d_in[9];
    const float* W_enc      = (const float*)d_in[10];
    const float* b_enc      = (const float*)d_in[11];
    const float* W_pred     = (const float*)d_in[12];
    const float* b_pred     = (const float*)d_in[13];
    const float* W_gain     = (const float*)d_in[14];
    const float* b_gain     = (const float*)d_in[15];
    float* out = (float*)d_out;
    u16* ws = (u16*)d_ws;

    kconv_all<<<3520, 256, 0, stream>>>(W_up, W_down, W_post, W_enc, W_gain, W_pred, ws);
    kfused<<<1024, 1024, 0, stream>>>(x_col, z_hat_prev, gamma, beta,
                                      b_enc, b_pred, b_gain, b_up, b_down, b_post,
                                      ws, out);
}